// Round 1
// baseline (2756.534 us; speedup 1.0000x reference)
//
#include <hip/hip_runtime.h>
#include <hip/hip_bf16.h>
#include <math.h>

typedef __bf16 bf16_t;
typedef __bf16 bf16x4 __attribute__((ext_vector_type(4)));
typedef __bf16 bf16x8 __attribute__((ext_vector_type(8)));
typedef float f32x4 __attribute__((ext_vector_type(4)));

#define SEQ 2048
#define NTOK 4096
#define MLA_SCALE 0.07216878364870322f
#define LN_EPS 1e-5f

// ---------------------------------------------------------------------------
// NT GEMM: C[M,N] = A[M,K] * B[N,K]^T   (A,B fp32 row-major, bf16 MFMA compute)
// 128x128 tile, BK=32, 256 threads (4 waves, each 64x64 via 4x4 mfma 16x16x32)
// ---------------------------------------------------------------------------
__global__ __launch_bounds__(256, 2)
void gemm_nt_bf16(const float* __restrict__ A, const float* __restrict__ B,
                  float* __restrict__ C, int M, int N, int K) {
    __shared__ bf16_t As[128][40];   // stride 40 bf16 = 80B -> conflict-benign
    __shared__ bf16_t Bs[128][40];
    const int tid = threadIdx.x;
    const int bm = blockIdx.y, bn = blockIdx.x;
    const int lane = tid & 63;
    const int w = tid >> 6;
    const int wm = (w >> 1) * 64, wn = (w & 1) * 64;
    const int lr = lane & 15, kh = lane >> 4;

    f32x4 acc[4][4];
    for (int i = 0; i < 4; ++i)
        for (int j = 0; j < 4; ++j)
            acc[i][j] = 0.0f;

    const int r0 = tid >> 3;          // staging row (+32*i)
    const int c0 = (tid & 7) * 4;     // staging col (floats)

    for (int kt = 0; kt < K; kt += 32) {
        __syncthreads();
        for (int i = 0; i < 4; ++i) {
            int r = r0 + 32 * i;
            float4 va = *(const float4*)(A + (size_t)(bm * 128 + r) * K + kt + c0);
            bf16x4 pa = { (bf16_t)va.x, (bf16_t)va.y, (bf16_t)va.z, (bf16_t)va.w };
            *(bf16x4*)&As[r][c0] = pa;
            int rb = bn * 128 + r;
            float4 vb = { 0.0f, 0.0f, 0.0f, 0.0f };
            if (rb < N) vb = *(const float4*)(B + (size_t)rb * K + kt + c0);
            bf16x4 pb = { (bf16_t)vb.x, (bf16_t)vb.y, (bf16_t)vb.z, (bf16_t)vb.w };
            *(bf16x4*)&Bs[r][c0] = pb;
        }
        __syncthreads();
        bf16x8 af[4], bfr[4];
        for (int im = 0; im < 4; ++im)
            af[im] = *(const bf16x8*)&As[wm + im * 16 + lr][kh * 8];
        for (int jn = 0; jn < 4; ++jn)
            bfr[jn] = *(const bf16x8*)&Bs[wn + jn * 16 + lr][kh * 8];
        for (int im = 0; im < 4; ++im)
            for (int jn = 0; jn < 4; ++jn)
                acc[im][jn] = __builtin_amdgcn_mfma_f32_16x16x32_bf16(
                    af[im], bfr[jn], acc[im][jn], 0, 0, 0);
    }

    const int rg = (lane >> 4) * 4;  // C/D: row=(lane>>4)*4+reg, col=lane&15
    for (int im = 0; im < 4; ++im) {
        for (int jn = 0; jn < 4; ++jn) {
            int col = bn * 128 + wn + jn * 16 + lr;
            if (col >= N) continue;
            size_t rowb = (size_t)(bm * 128 + wm + im * 16 + rg);
            for (int rr = 0; rr < 4; ++rr)
                C[(rowb + rr) * N + col] = acc[im][jn][rr];
        }
    }
}

// ---------------------------------------------------------------------------
// Fused: layernorm(kv) -> kvn, rope(k_pe) -> kpe, rope(q_pe) in-place on q
// one block per token row m (4096 blocks x 256 threads)
// ---------------------------------------------------------------------------
__global__ __launch_bounds__(256)
void rope_ln_kernel(float* __restrict__ q, const float* __restrict__ kv_all,
                    const float* __restrict__ lnw, const float* __restrict__ lnb,
                    float* __restrict__ kvn, float* __restrict__ kpe,
                    const int* __restrict__ start_pos) {
    const int m = blockIdx.x;
    const int tid = threadIdx.x;
    const int s = m & (SEQ - 1);
    const float pos = (float)(start_pos[0] + s);
    __shared__ float red[8];
    __shared__ float stats[2];

    const float* kvrow = kv_all + (size_t)m * 576;
    float v0 = kvrow[tid], v1 = kvrow[tid + 256];
    float ssum = v0 + v1, ssq = v0 * v0 + v1 * v1;
    for (int off = 32; off > 0; off >>= 1) {
        ssum += __shfl_down(ssum, off);
        ssq  += __shfl_down(ssq, off);
    }
    const int lane = tid & 63, wid = tid >> 6;
    if (lane == 0) { red[wid] = ssum; red[4 + wid] = ssq; }
    __syncthreads();
    if (tid == 0) {
        float ts = red[0] + red[1] + red[2] + red[3];
        float tq = red[4] + red[5] + red[6] + red[7];
        float mu = ts * (1.0f / 512.0f);
        float var = tq * (1.0f / 512.0f) - mu * mu;
        stats[0] = mu;
        stats[1] = rsqrtf(var + LN_EPS);
    }
    __syncthreads();
    float mu = stats[0], rstd = stats[1];
    kvn[(size_t)m * 512 + tid]       = (v0 - mu) * rstd * lnw[tid] + lnb[tid];
    kvn[(size_t)m * 512 + tid + 256] = (v1 - mu) * rstd * lnw[tid + 256] + lnb[tid + 256];

    // rope on k_pe (64 dims -> 32 pairs)
    if (tid < 32) {
        int j = tid;
        float inv = expf(-(float)j * 0.2878231366242554f);  // 10000^(-j/32)
        float ang = pos * inv;
        float c = cosf(ang), sn = sinf(ang);
        float x1 = kvrow[512 + j], x2 = kvrow[544 + j];
        kpe[(size_t)m * 64 + j]      = x1 * c - x2 * sn;
        kpe[(size_t)m * 64 + 32 + j] = x2 * c + x1 * sn;
    }
    // rope on q_pe: 16 heads x 32 pairs = 512 pairs
    for (int i = 0; i < 2; ++i) {
        int p = tid + 256 * i;
        int h = p >> 5, j = p & 31;
        float inv = expf(-(float)j * 0.2878231366242554f);
        float ang = pos * inv;
        float c = cosf(ang), sn = sinf(ang);
        size_t base = (size_t)m * 3072 + h * 192 + 128;
        float x1 = q[base + j], x2 = q[base + 32 + j];
        q[base + j]      = x1 * c - x2 * sn;
        q[base + 32 + j] = x2 * c + x1 * sn;
    }
}

// ---------------------------------------------------------------------------
// Flash attention (fp32 VALU compute, bf16 LDS staging)
// block = (q-tile of 32 rows, head, batch); 256 threads
// ---------------------------------------------------------------------------
__global__ __launch_bounds__(256)
void attn_kernel(const float* __restrict__ q, const float* __restrict__ knv,
                 const float* __restrict__ kpe, float* __restrict__ out) {
    const int qt = blockIdx.x, h = blockIdx.y, b = blockIdx.z;
    const int tid = threadIdx.x;
    __shared__ bf16_t Qs[32][196];
    __shared__ bf16_t Ks[32][196];
    __shared__ bf16_t Vs[32][132];
    __shared__ float  Ps[32][33];
    __shared__ float  mrow[32], lrow[32], crow[32];
    const int q0 = qt * 32;
    const size_t bS = (size_t)b * SEQ;

    // load Q tile (32 x 192)
    for (int i = 0; i < 6; ++i) {
        int f = tid + 256 * i;
        int r = f / 48, d4 = (f % 48) * 4;
        float4 v = *(const float4*)(q + (bS + q0 + r) * 3072 + h * 192 + d4);
        bf16x4 p = { (bf16_t)v.x, (bf16_t)v.y, (bf16_t)v.z, (bf16_t)v.w };
        *(bf16x4*)&Qs[r][d4] = p;
    }
    if (tid < 32) { mrow[tid] = -INFINITY; lrow[tid] = 0.0f; }
    float O[4][4];
    for (int i = 0; i < 4; ++i)
        for (int j = 0; j < 4; ++j) O[i][j] = 0.0f;

    const int sr0 = (tid >> 5) * 4;
    const int sc  = tid & 31;
    const int d0  = (tid & 31) * 4;

    for (int kt = 0; kt <= qt; ++kt) {
        __syncthreads();
        // stage K(nope) + V
        for (int i = 0; i < 4; ++i) {
            int f = tid + 256 * i;
            int c = f >> 5, d4 = (f & 31) * 4;
            const float* krow = knv + (bS + kt * 32 + c) * 4096 + h * 256;
            float4 v = *(const float4*)(krow + d4);
            bf16x4 p = { (bf16_t)v.x, (bf16_t)v.y, (bf16_t)v.z, (bf16_t)v.w };
            *(bf16x4*)&Ks[c][d4] = p;
            float4 vv = *(const float4*)(krow + 128 + d4);
            bf16x4 pv = { (bf16_t)vv.x, (bf16_t)vv.y, (bf16_t)vv.z, (bf16_t)vv.w };
            *(bf16x4*)&Vs[c][d4] = pv;
        }
        // stage K(rope), shared across heads
        for (int i = 0; i < 2; ++i) {
            int f = tid + 256 * i;
            int c = f >> 4, d4 = (f & 15) * 4;
            float4 v = *(const float4*)(kpe + (bS + kt * 32 + c) * 64 + d4);
            bf16x4 p = { (bf16_t)v.x, (bf16_t)v.y, (bf16_t)v.z, (bf16_t)v.w };
            *(bf16x4*)&Ks[c][128 + d4] = p;
        }
        __syncthreads();
        // scores: S[sr0+i][sc]
        float sacc[4] = { 0.f, 0.f, 0.f, 0.f };
        for (int d = 0; d < 192; d += 4) {
            bf16x4 kv4 = *(const bf16x4*)&Ks[sc][d];
            float k0 = kv4[0], k1 = kv4[1], k2 = kv4[2], k3 = kv4[3];
            for (int i = 0; i < 4; ++i) {
                bf16x4 qv4 = *(const bf16x4*)&Qs[sr0 + i][d];
                sacc[i] += (float)qv4[0] * k0 + (float)qv4[1] * k1 +
                           (float)qv4[2] * k2 + (float)qv4[3] * k3;
            }
        }
        int tcol = kt * 32 + sc;
        for (int i = 0; i < 4; ++i) {
            int srow = q0 + sr0 + i;
            float sv = sacc[i] * MLA_SCALE;
            if (tcol > srow) sv = -1e30f;
            Ps[sr0 + i][sc] = sv;
        }
        __syncthreads();
        // online softmax (one thread per row)
        if (tid < 32) {
            int r = tid;
            float mo = mrow[r], mx = mo;
            for (int c = 0; c < 32; ++c) mx = fmaxf(mx, Ps[r][c]);
            float cr = __expf(mo - mx);
            float sum = lrow[r] * cr;
            for (int c = 0; c < 32; ++c) {
                float p = __expf(Ps[r][c] - mx);
                Ps[r][c] = p;
                sum += p;
            }
            mrow[r] = mx; lrow[r] = sum; crow[r] = cr;
        }
        __syncthreads();
        // rescale + PV
        for (int i = 0; i < 4; ++i) {
            float cr = crow[sr0 + i];
            for (int j = 0; j < 4; ++j) O[i][j] *= cr;
        }
        for (int t = 0; t < 32; ++t) {
            bf16x4 v4 = *(const bf16x4*)&Vs[t][d0];
            float vv0 = v4[0], vv1 = v4[1], vv2 = v4[2], vv3 = v4[3];
            for (int i = 0; i < 4; ++i) {
                float p = Ps[sr0 + i][t];
                O[i][0] += p * vv0; O[i][1] += p * vv1;
                O[i][2] += p * vv2; O[i][3] += p * vv3;
            }
        }
    }
    for (int i = 0; i < 4; ++i) {
        float inv = 1.0f / lrow[sr0 + i];
        size_t rowb = (bS + q0 + sr0 + i) * 2048 + h * 128 + d0;
        out[rowb + 0] = O[i][0] * inv;
        out[rowb + 1] = O[i][1] * inv;
        out[rowb + 2] = O[i][2] * inv;
        out[rowb + 3] = O[i][3] * inv;
    }
}

// ---------------------------------------------------------------------------
extern "C" void kernel_launch(void* const* d_in, const int* in_sizes, int n_in,
                              void* d_out, int out_size, void* d_ws, size_t ws_size,
                              hipStream_t stream) {
    const float* x     = (const float*)d_in[0];
    const float* wq    = (const float*)d_in[1];
    const float* wkv_a = (const float*)d_in[2];
    const float* lnw   = (const float*)d_in[3];
    const float* lnb   = (const float*)d_in[4];
    const float* wkv_b = (const float*)d_in[5];
    const float* wo    = (const float*)d_in[6];
    const int* start_pos = (const int*)d_in[7];
    float* out = (float*)d_out;

    float* ws     = (float*)d_ws;
    float* q      = ws;                    // 4096*3072 = 12582912
    float* kv_all = q + 12582912;          // 4096*576  =  2359296
    float* kvn    = kv_all + 2359296;      // 4096*512  =  2097152
    float* kpe    = kvn + 2097152;         // 4096*64   =   262144
    float* knv    = kpe + 262144;          // 4096*4096 = 16777216
    float* ao     = knv + 16777216;        // 4096*2048 =  8388608

    // q = x @ wq.T
    gemm_nt_bf16<<<dim3(24, 32), 256, 0, stream>>>(x, wq, q, 4096, 3072, 2048);
    // kv_all = x @ wkv_a.T
    gemm_nt_bf16<<<dim3(5, 32), 256, 0, stream>>>(x, wkv_a, kv_all, 4096, 576, 2048);
    // layernorm + rope
    rope_ln_kernel<<<4096, 256, 0, stream>>>(q, kv_all, lnw, lnb, kvn, kpe, start_pos);
    // k_nope & v = kvn @ wkv_b.T  (interleaved per head: 128 k_nope + 128 v)
    gemm_nt_bf16<<<dim3(32, 32), 256, 0, stream>>>(kvn, wkv_b, knv, 4096, 4096, 512);
    // attention
    attn_kernel<<<dim3(64, 16, 2), 256, 0, stream>>>(q, knv, kpe, ao);
    // out = ao @ wo.T
    gemm_nt_bf16<<<dim3(16, 32), 256, 0, stream>>>(ao, wo, out, 4096, 2048, 2048);
}

// Round 2
// 1186.602 us; speedup vs baseline: 2.3230x; 2.3230x over previous
//
#include <hip/hip_runtime.h>
#include <hip/hip_bf16.h>
#include <math.h>

typedef __bf16 bf16_t;
typedef __bf16 bf16x4 __attribute__((ext_vector_type(4)));
typedef __bf16 bf16x8 __attribute__((ext_vector_type(8)));
typedef float f32x4 __attribute__((ext_vector_type(4)));

#define SEQ 2048
#define NTOK 4096
#define MLA_SCALE 0.07216878364870322f
#define LN_EPS 1e-5f

// ---------------------------------------------------------------------------
// NT GEMM: C[M,N] = A[M,K] * B[N,K]^T   (A,B fp32 row-major, bf16 MFMA compute)
// ---------------------------------------------------------------------------
__global__ __launch_bounds__(256, 2)
void gemm_nt_bf16(const float* __restrict__ A, const float* __restrict__ B,
                  float* __restrict__ C, int M, int N, int K) {
    __shared__ bf16_t As[128][40];
    __shared__ bf16_t Bs[128][40];
    const int tid = threadIdx.x;
    const int bm = blockIdx.y, bn = blockIdx.x;
    const int lane = tid & 63;
    const int w = tid >> 6;
    const int wm = (w >> 1) * 64, wn = (w & 1) * 64;
    const int lr = lane & 15, kh = lane >> 4;

    f32x4 acc[4][4];
    for (int i = 0; i < 4; ++i)
        for (int j = 0; j < 4; ++j)
            acc[i][j] = 0.0f;

    const int r0 = tid >> 3;
    const int c0 = (tid & 7) * 4;

    for (int kt = 0; kt < K; kt += 32) {
        __syncthreads();
        for (int i = 0; i < 4; ++i) {
            int r = r0 + 32 * i;
            float4 va = *(const float4*)(A + (size_t)(bm * 128 + r) * K + kt + c0);
            bf16x4 pa = { (bf16_t)va.x, (bf16_t)va.y, (bf16_t)va.z, (bf16_t)va.w };
            *(bf16x4*)&As[r][c0] = pa;
            int rb = bn * 128 + r;
            float4 vb = { 0.0f, 0.0f, 0.0f, 0.0f };
            if (rb < N) vb = *(const float4*)(B + (size_t)rb * K + kt + c0);
            bf16x4 pb = { (bf16_t)vb.x, (bf16_t)vb.y, (bf16_t)vb.z, (bf16_t)vb.w };
            *(bf16x4*)&Bs[r][c0] = pb;
        }
        __syncthreads();
        bf16x8 af[4], bfr[4];
        for (int im = 0; im < 4; ++im)
            af[im] = *(const bf16x8*)&As[wm + im * 16 + lr][kh * 8];
        for (int jn = 0; jn < 4; ++jn)
            bfr[jn] = *(const bf16x8*)&Bs[wn + jn * 16 + lr][kh * 8];
        for (int im = 0; im < 4; ++im)
            for (int jn = 0; jn < 4; ++jn)
                acc[im][jn] = __builtin_amdgcn_mfma_f32_16x16x32_bf16(
                    af[im], bfr[jn], acc[im][jn], 0, 0, 0);
    }

    const int rg = (lane >> 4) * 4;
    for (int im = 0; im < 4; ++im) {
        for (int jn = 0; jn < 4; ++jn) {
            int col = bn * 128 + wn + jn * 16 + lr;
            if (col >= N) continue;
            size_t rowb = (size_t)(bm * 128 + wm + im * 16 + rg);
            for (int rr = 0; rr < 4; ++rr)
                C[(rowb + rr) * N + col] = acc[im][jn][rr];
        }
    }
}

// ---------------------------------------------------------------------------
// Fused: layernorm(kv) -> kvn, rope(k_pe) -> kpe, rope(q_pe) in-place on q
// ---------------------------------------------------------------------------
__global__ __launch_bounds__(256)
void rope_ln_kernel(float* __restrict__ q, const float* __restrict__ kv_all,
                    const float* __restrict__ lnw, const float* __restrict__ lnb,
                    float* __restrict__ kvn, float* __restrict__ kpe,
                    const int* __restrict__ start_pos) {
    const int m = blockIdx.x;
    const int tid = threadIdx.x;
    const int s = m & (SEQ - 1);
    const float pos = (float)(start_pos[0] + s);
    __shared__ float red[8];
    __shared__ float stats[2];

    const float* kvrow = kv_all + (size_t)m * 576;
    float v0 = kvrow[tid], v1 = kvrow[tid + 256];
    float ssum = v0 + v1, ssq = v0 * v0 + v1 * v1;
    for (int off = 32; off > 0; off >>= 1) {
        ssum += __shfl_down(ssum, off);
        ssq  += __shfl_down(ssq, off);
    }
    const int lane = tid & 63, wid = tid >> 6;
    if (lane == 0) { red[wid] = ssum; red[4 + wid] = ssq; }
    __syncthreads();
    if (tid == 0) {
        float ts = red[0] + red[1] + red[2] + red[3];
        float tq = red[4] + red[5] + red[6] + red[7];
        float mu = ts * (1.0f / 512.0f);
        float var = tq * (1.0f / 512.0f) - mu * mu;
        stats[0] = mu;
        stats[1] = rsqrtf(var + LN_EPS);
    }
    __syncthreads();
    float mu = stats[0], rstd = stats[1];
    kvn[(size_t)m * 512 + tid]       = (v0 - mu) * rstd * lnw[tid] + lnb[tid];
    kvn[(size_t)m * 512 + tid + 256] = (v1 - mu) * rstd * lnw[tid + 256] + lnb[tid + 256];

    if (tid < 32) {
        int j = tid;
        float inv = expf(-(float)j * 0.2878231366242554f);
        float ang = pos * inv;
        float c = cosf(ang), sn = sinf(ang);
        float x1 = kvrow[512 + j], x2 = kvrow[544 + j];
        kpe[(size_t)m * 64 + j]      = x1 * c - x2 * sn;
        kpe[(size_t)m * 64 + 32 + j] = x2 * c + x1 * sn;
    }
    for (int i = 0; i < 2; ++i) {
        int p = tid + 256 * i;
        int h = p >> 5, j = p & 31;
        float inv = expf(-(float)j * 0.2878231366242554f);
        float ang = pos * inv;
        float c = cosf(ang), sn = sinf(ang);
        size_t base = (size_t)m * 3072 + h * 192 + 128;
        float x1 = q[base + j], x2 = q[base + 32 + j];
        q[base + j]      = x1 * c - x2 * sn;
        q[base + 32 + j] = x2 * c + x1 * sn;
    }
}

// ---------------------------------------------------------------------------
// pack_v: V slice of knv (fp32, [token][h*256+128..256]) -> Vt bf16 [b,h][d][t]
// block = (t-tile 64, h, b); LDS transpose
// ---------------------------------------------------------------------------
__global__ __launch_bounds__(256)
void pack_v(const float* __restrict__ knv, bf16_t* __restrict__ vt) {
    __shared__ bf16_t Vs[64][132];
    const int tt = blockIdx.x, h = blockIdx.y, b = blockIdx.z;
    const int tid = threadIdx.x;
    const size_t bS = (size_t)b * SEQ;
    const int t0 = tt * 64;

    for (int i = 0; i < 8; ++i) {
        int c = tid + 256 * i;
        int t = c >> 5, c4 = (c & 31) * 4;
        float4 v = *(const float4*)(knv + (bS + t0 + t) * 4096 + h * 256 + 128 + c4);
        bf16x4 p = { (bf16_t)v.x, (bf16_t)v.y, (bf16_t)v.z, (bf16_t)v.w };
        *(bf16x4*)&Vs[t][c4] = p;
    }
    __syncthreads();
    const size_t vbase = ((size_t)(b * 16 + h) * 128) * SEQ;
    for (int i = 0; i < 4; ++i) {
        int c = tid + 256 * i;
        int d = c >> 3, t8 = (c & 7) * 8;
        bf16x8 o;
        for (int j = 0; j < 8; ++j) o[j] = Vs[t8 + j][d];
        *(bf16x8*)(vt + vbase + (size_t)d * SEQ + t0 + t8) = o;
    }
}

// ---------------------------------------------------------------------------
// MFMA flash attention.
// grid (32 qtiles, 16 h, 2 b), 256 thr = 4 waves; QBLK=64 (16 rows/wave), KVBLK=64
// ---------------------------------------------------------------------------
__global__ __launch_bounds__(256, 2)
void attn_mfma(const float* __restrict__ q, const float* __restrict__ knv,
               const float* __restrict__ kpe, const bf16_t* __restrict__ vt,
               float* __restrict__ out) {
    __shared__ bf16_t Ks[64][200];       // 64 kv rows x 192 feat (nope+rope)
    __shared__ bf16_t Vts[128][72];      // d x t
    __shared__ bf16_t Pls[4][16][72];    // per-wave P tiles

    const int qt = 31 - blockIdx.x;      // heavy tiles first
    const int h = blockIdx.y, b = blockIdx.z;
    const int tid = threadIdx.x;
    const int lane = tid & 63, w = tid >> 6;
    const int lr = lane & 15, kh = lane >> 4;
    const size_t bS = (size_t)b * SEQ;
    const int q0 = qt * 64;
    const int myrow = q0 + w * 16;       // wave's first q row

    // Q fragments: 6 k-steps of 32 over 192 dims, bf16x8 each
    bf16x8 qf[6];
    {
        const float* qrow = q + (bS + myrow + lr) * 3072 + h * 192;
        for (int ks = 0; ks < 6; ++ks) {
            float4 a = *(const float4*)(qrow + ks * 32 + kh * 8);
            float4 c = *(const float4*)(qrow + ks * 32 + kh * 8 + 4);
            qf[ks][0] = (bf16_t)a.x; qf[ks][1] = (bf16_t)a.y;
            qf[ks][2] = (bf16_t)a.z; qf[ks][3] = (bf16_t)a.w;
            qf[ks][4] = (bf16_t)c.x; qf[ks][5] = (bf16_t)c.y;
            qf[ks][6] = (bf16_t)c.z; qf[ks][7] = (bf16_t)c.w;
        }
    }

    f32x4 O[8];
    for (int i = 0; i < 8; ++i) O[i] = 0.0f;
    float m_r[4], l_r[4];
    for (int r = 0; r < 4; ++r) { m_r[r] = -1e30f; l_r[r] = 0.0f; }

    const size_t vtbase = ((size_t)(b * 16 + h) * 128) * SEQ;

    for (int kt = 0; kt <= qt; ++kt) {
        const int t0 = kt * 64;
        __syncthreads();
        // stage K nope (fp32 -> bf16)
        for (int i = 0; i < 8; ++i) {
            int c = tid + 256 * i;
            int t = c >> 5, c4 = (c & 31) * 4;
            float4 v = *(const float4*)(knv + (bS + t0 + t) * 4096 + h * 256 + c4);
            bf16x4 p = { (bf16_t)v.x, (bf16_t)v.y, (bf16_t)v.z, (bf16_t)v.w };
            *(bf16x4*)&Ks[t][c4] = p;
        }
        // stage K rope
        for (int i = 0; i < 4; ++i) {
            int c = tid + 256 * i;
            int t = c >> 4, c4 = (c & 15) * 4;
            float4 v = *(const float4*)(kpe + (bS + t0 + t) * 64 + c4);
            bf16x4 p = { (bf16_t)v.x, (bf16_t)v.y, (bf16_t)v.z, (bf16_t)v.w };
            *(bf16x4*)&Ks[t][128 + c4] = p;
        }
        // stage Vt (bf16 16B chunks)
        for (int i = 0; i < 4; ++i) {
            int c = tid + 256 * i;
            int d = c >> 3, t8 = (c & 7) * 8;
            *(bf16x8*)&Vts[d][t8] = *(const bf16x8*)(vt + vtbase + (size_t)d * SEQ + t0 + t8);
        }
        __syncthreads();

        // QK^T: 4 t-tiles x 6 k-steps
        f32x4 sacc[4];
        for (int j = 0; j < 4; ++j) sacc[j] = 0.0f;
        for (int ks = 0; ks < 6; ++ks) {
            for (int j = 0; j < 4; ++j) {
                bf16x8 bfr = *(const bf16x8*)&Ks[j * 16 + lr][ks * 32 + kh * 8];
                sacc[j] = __builtin_amdgcn_mfma_f32_16x16x32_bf16(qf[ks], bfr, sacc[j], 0, 0, 0);
            }
        }

        // scale + causal mask
        float sv[4][4];
        for (int j = 0; j < 4; ++j) {
            int tcol = t0 + j * 16 + lr;
            for (int rr = 0; rr < 4; ++rr) {
                int qrow = myrow + kh * 4 + rr;
                float v = sacc[j][rr] * MLA_SCALE;
                sv[j][rr] = (tcol > qrow) ? -1e30f : v;
            }
        }
        // online softmax: rows live across 16-lane groups
        float corr[4];
        for (int rr = 0; rr < 4; ++rr) {
            float mx = fmaxf(fmaxf(sv[0][rr], sv[1][rr]), fmaxf(sv[2][rr], sv[3][rr]));
            mx = fmaxf(mx, __shfl_xor(mx, 1));
            mx = fmaxf(mx, __shfl_xor(mx, 2));
            mx = fmaxf(mx, __shfl_xor(mx, 4));
            mx = fmaxf(mx, __shfl_xor(mx, 8));
            float mnew = fmaxf(m_r[rr], mx);
            float cr = __expf(m_r[rr] - mnew);
            float psum = 0.0f;
            for (int j = 0; j < 4; ++j) {
                float p = __expf(sv[j][rr] - mnew);
                sv[j][rr] = p;
                psum += p;
            }
            psum += __shfl_xor(psum, 1);
            psum += __shfl_xor(psum, 2);
            psum += __shfl_xor(psum, 4);
            psum += __shfl_xor(psum, 8);
            l_r[rr] = l_r[rr] * cr + psum;
            m_r[rr] = mnew;
            corr[rr] = cr;
        }
        // rescale O
        for (int dt = 0; dt < 8; ++dt)
            for (int rr = 0; rr < 4; ++rr)
                O[dt][rr] *= corr[rr];
        // write P to per-wave LDS (bf16)
        for (int rr = 0; rr < 4; ++rr)
            for (int j = 0; j < 4; ++j)
                Pls[w][kh * 4 + rr][j * 16 + lr] = (bf16_t)sv[j][rr];
        // PV: A = P[16q][64t], B = Vt[d][t]
        bf16x8 pa0 = *(const bf16x8*)&Pls[w][lr][kh * 8];
        bf16x8 pa1 = *(const bf16x8*)&Pls[w][lr][32 + kh * 8];
        for (int dt = 0; dt < 8; ++dt) {
            bf16x8 b0 = *(const bf16x8*)&Vts[dt * 16 + lr][kh * 8];
            O[dt] = __builtin_amdgcn_mfma_f32_16x16x32_bf16(pa0, b0, O[dt], 0, 0, 0);
            bf16x8 b1 = *(const bf16x8*)&Vts[dt * 16 + lr][32 + kh * 8];
            O[dt] = __builtin_amdgcn_mfma_f32_16x16x32_bf16(pa1, b1, O[dt], 0, 0, 0);
        }
    }

    // epilogue
    for (int rr = 0; rr < 4; ++rr) {
        float inv = 1.0f / l_r[rr];
        size_t rowb = (bS + myrow + kh * 4 + rr) * 2048 + h * 128;
        for (int dt = 0; dt < 8; ++dt)
            out[rowb + dt * 16 + lr] = O[dt][rr] * inv;
    }
}

// ---------------------------------------------------------------------------
extern "C" void kernel_launch(void* const* d_in, const int* in_sizes, int n_in,
                              void* d_out, int out_size, void* d_ws, size_t ws_size,
                              hipStream_t stream) {
    const float* x     = (const float*)d_in[0];
    const float* wq    = (const float*)d_in[1];
    const float* wkv_a = (const float*)d_in[2];
    const float* lnw   = (const float*)d_in[3];
    const float* lnb   = (const float*)d_in[4];
    const float* wkv_b = (const float*)d_in[5];
    const float* wo    = (const float*)d_in[6];
    const int* start_pos = (const int*)d_in[7];
    float* out = (float*)d_out;

    float* ws     = (float*)d_ws;
    float* q      = ws;                    // 4096*3072
    float* kv_all = q + 12582912;          // 4096*576
    float* kvn    = kv_all + 2359296;      // 4096*512
    float* kpe    = kvn + 2097152;         // 4096*64
    float* knv    = kpe + 262144;          // 4096*4096
    float* ao     = knv + 16777216;        // 4096*2048
    // Vt bf16 overlays kv_all+kvn (dead after knv GEMM): needs 16777216 bf16
    bf16_t* vt    = (bf16_t*)kv_all;       // 2x2359296+2097152 floats >= 8.4M floats ok

    gemm_nt_bf16<<<dim3(24, 32), 256, 0, stream>>>(x, wq, q, 4096, 3072, 2048);
    gemm_nt_bf16<<<dim3(5, 32), 256, 0, stream>>>(x, wkv_a, kv_all, 4096, 576, 2048);
    rope_ln_kernel<<<4096, 256, 0, stream>>>(q, kv_all, lnw, lnb, kvn, kpe, start_pos);
    gemm_nt_bf16<<<dim3(32, 32), 256, 0, stream>>>(kvn, wkv_b, knv, 4096, 4096, 512);
    pack_v<<<dim3(32, 16, 2), 256, 0, stream>>>(knv, vt);
    attn_mfma<<<dim3(32, 16, 2), 256, 0, stream>>>(q, knv, kpe, vt, ao);
    gemm_nt_bf16<<<dim3(16, 32), 256, 0, stream>>>(ao, wo, out, 4096, 2048, 2048);
}

// Round 3
// 355.197 us; speedup vs baseline: 7.7606x; 3.3407x over previous
//
#include <hip/hip_runtime.h>
#include <hip/hip_bf16.h>
#include <math.h>

typedef __bf16 bf16_t;
typedef __bf16 bf16x4 __attribute__((ext_vector_type(4)));
typedef __bf16 bf16x8 __attribute__((ext_vector_type(8)));
typedef float f32x4 __attribute__((ext_vector_type(4)));

#define SEQ 2048
#define MLA_SCALE 0.07216878364870322f
#define LN_EPS 1e-5f

__device__ __forceinline__ void gload_lds16(const bf16_t* g, bf16_t* l) {
    __builtin_amdgcn_global_load_lds(
        (const __attribute__((address_space(1))) uint32_t*)(const void*)g,
        (__attribute__((address_space(3))) uint32_t*)(void*)l, 16, 0, 0);
}

// ---------------------------------------------------------------------------
// fp32 -> bf16 convert (vectorized, grid-stride)
// ---------------------------------------------------------------------------
__global__ __launch_bounds__(256)
void cvt_f32_bf16(const float* __restrict__ in, bf16_t* __restrict__ out, int n4) {
    for (int i = blockIdx.x * 256 + threadIdx.x; i < n4; i += gridDim.x * 256) {
        float4 v = ((const float4*)in)[i];
        bf16x4 p = { (bf16_t)v.x, (bf16_t)v.y, (bf16_t)v.z, (bf16_t)v.w };
        ((bf16x4*)out)[i] = p;
    }
}

// ---------------------------------------------------------------------------
// m97-structure GEMM core: C[M,N] = A[M,K] * B[N,K]^T, bf16 in, fp32 acc.
// 128x128 tile, BK=32, 4 waves, global_load_lds staging, linear LDS.
// ---------------------------------------------------------------------------
__device__ __forceinline__ void gemm_core(const bf16_t* __restrict__ A,
                                          const bf16_t* __restrict__ B,
                                          int N, int K, int bm, int bn,
                                          bf16_t* As, bf16_t* Bs,
                                          f32x4 (&acc)[4][4]) {
    const int tid = threadIdx.x;
    const int lane = tid & 63, w = tid >> 6;
    const int lr = lane & 15, kh = lane >> 4;
    const int wm = (w >> 1) * 64, wn = (w & 1) * 64;
    const int subrow = lane >> 2;           // 0..15 (4 lanes per 64B row)
    const int colel = (lane & 3) * 8;       // 0,8,16,24

    const int rA = bm * 128 + 32 * w + subrow;
    const int rB = bn * 128 + 32 * w + subrow;
    const int rb1 = (rB < N) ? rB : (N - 1);
    const int rb2 = (rB + 16 < N) ? (rB + 16) : (N - 1);

    for (int kt = 0; kt < K; kt += 32) {
        __syncthreads();
        gload_lds16(A + (size_t)rA * K + kt + colel,        As + (2 * w) * 512);
        gload_lds16(A + (size_t)(rA + 16) * K + kt + colel, As + (2 * w + 1) * 512);
        gload_lds16(B + (size_t)rb1 * K + kt + colel,       Bs + (2 * w) * 512);
        gload_lds16(B + (size_t)rb2 * K + kt + colel,       Bs + (2 * w + 1) * 512);
        __syncthreads();
        bf16x8 af[4], bfr[4];
        #pragma unroll
        for (int im = 0; im < 4; ++im)
            af[im] = *(const bf16x8*)(As + (wm + im * 16 + lr) * 32 + kh * 8);
        #pragma unroll
        for (int jn = 0; jn < 4; ++jn)
            bfr[jn] = *(const bf16x8*)(Bs + (wn + jn * 16 + lr) * 32 + kh * 8);
        #pragma unroll
        for (int im = 0; im < 4; ++im)
            #pragma unroll
            for (int jn = 0; jn < 4; ++jn)
                acc[im][jn] = __builtin_amdgcn_mfma_f32_16x16x32_bf16(
                    af[im], bfr[jn], acc[im][jn], 0, 0, 0);
    }
}

__global__ __launch_bounds__(256)
void gemm_nt(const bf16_t* __restrict__ A, const bf16_t* __restrict__ B,
             float* __restrict__ C, int M, int N, int K) {
    __shared__ bf16_t As[4096], Bs[4096];
    f32x4 acc[4][4];
    #pragma unroll
    for (int i = 0; i < 4; ++i)
        #pragma unroll
        for (int j = 0; j < 4; ++j) acc[i][j] = 0.0f;
    gemm_core(A, B, N, K, blockIdx.y, blockIdx.x, As, Bs, acc);

    const int tid = threadIdx.x, lane = tid & 63, w = tid >> 6;
    const int lr = lane & 15, rg = (lane >> 4) * 4;
    const int wm = (w >> 1) * 64, wn = (w & 1) * 64;
    #pragma unroll
    for (int im = 0; im < 4; ++im)
        #pragma unroll
        for (int jn = 0; jn < 4; ++jn) {
            int col = blockIdx.x * 128 + wn + jn * 16 + lr;
            if (col >= N) continue;
            size_t rowb = (size_t)(blockIdx.y * 128 + wm + im * 16 + rg);
            #pragma unroll
            for (int rr = 0; rr < 4; ++rr)
                C[(rowb + rr) * N + col] = acc[im][jn][rr];
        }
}

// kv_b GEMM with packing epilogue: M=4096 tokens, N=4096 (h*256+d), K=512.
// d<128 -> K_pack[b,h,t,192] (nope part); d>=128 -> Vt[b,h,d-128,t] (transposed)
__global__ __launch_bounds__(256)
void gemm_kvb_pack(const bf16_t* __restrict__ A, const bf16_t* __restrict__ B,
                   bf16_t* __restrict__ kpack, bf16_t* __restrict__ vt) {
    __shared__ bf16_t As[4096], Bs[4096];
    f32x4 acc[4][4];
    #pragma unroll
    for (int i = 0; i < 4; ++i)
        #pragma unroll
        for (int j = 0; j < 4; ++j) acc[i][j] = 0.0f;
    gemm_core(A, B, 4096, 512, blockIdx.y, blockIdx.x, As, Bs, acc);

    const int tid = threadIdx.x, lane = tid & 63, w = tid >> 6;
    const int lr = lane & 15, rg = (lane >> 4) * 4;
    const int wm = (w >> 1) * 64, wn = (w & 1) * 64;
    #pragma unroll
    for (int im = 0; im < 4; ++im)
        #pragma unroll
        for (int jn = 0; jn < 4; ++jn) {
            int n = blockIdx.x * 128 + wn + jn * 16 + lr;
            int h = n >> 8, d = n & 255;
            int trow = blockIdx.y * 128 + wm + im * 16 + rg;
            int b = trow >> 11, t = trow & 2047;
            if (d < 128) {
                bf16_t* p = kpack + ((size_t)(b * 16 + h) * SEQ + t) * 192 + d;
                #pragma unroll
                for (int rr = 0; rr < 4; ++rr)
                    p[rr * 192] = (bf16_t)acc[im][jn][rr];
            } else {
                bf16x4 pv = { (bf16_t)acc[im][jn][0], (bf16_t)acc[im][jn][1],
                              (bf16_t)acc[im][jn][2], (bf16_t)acc[im][jn][3] };
                *(bf16x4*)(vt + ((size_t)(b * 16 + h) * 128 + (d - 128)) * SEQ + t) = pv;
            }
        }
}

// ---------------------------------------------------------------------------
// Fused: layernorm(kv)->kvnb (bf16), rope(k_pe)->K_pack[...,128:192] broadcast
// to 16 heads (bf16), rope(q_pe) in place on q (fp32). One block per token.
// ---------------------------------------------------------------------------
__global__ __launch_bounds__(256)
void rope_ln(float* __restrict__ q, const float* __restrict__ kv_all,
             const float* __restrict__ lnw, const float* __restrict__ lnb,
             bf16_t* __restrict__ kvnb, bf16_t* __restrict__ kpack,
             const int* __restrict__ start_pos) {
    const int m = blockIdx.x;
    const int tid = threadIdx.x;
    const int b = m >> 11, t = m & 2047;
    const float pos = (float)(start_pos[0] + t);
    __shared__ float red[8];
    __shared__ float stats[2];
    __shared__ float kbuf[64];

    const float* kvrow = kv_all + (size_t)m * 576;
    float v0 = kvrow[tid], v1 = kvrow[tid + 256];
    float ssum = v0 + v1, ssq = v0 * v0 + v1 * v1;
    for (int off = 32; off > 0; off >>= 1) {
        ssum += __shfl_down(ssum, off);
        ssq  += __shfl_down(ssq, off);
    }
    const int lane = tid & 63, wid = tid >> 6;
    if (lane == 0) { red[wid] = ssum; red[4 + wid] = ssq; }
    __syncthreads();
    if (tid == 0) {
        float ts = red[0] + red[1] + red[2] + red[3];
        float tq = red[4] + red[5] + red[6] + red[7];
        float mu = ts * (1.0f / 512.0f);
        float var = tq * (1.0f / 512.0f) - mu * mu;
        stats[0] = mu;
        stats[1] = rsqrtf(var + LN_EPS);
    }
    if (tid < 32) {
        int j = tid;
        float inv = expf(-(float)j * 0.2878231366242554f);  // 10000^(-j/32)
        float ang = pos * inv;
        float c = cosf(ang), sn = sinf(ang);
        float x1 = kvrow[512 + j], x2 = kvrow[544 + j];
        kbuf[j]      = x1 * c - x2 * sn;
        kbuf[32 + j] = x2 * c + x1 * sn;
    }
    __syncthreads();
    float mu = stats[0], rstd = stats[1];
    kvnb[(size_t)m * 512 + tid]       = (bf16_t)((v0 - mu) * rstd * lnw[tid] + lnb[tid]);
    kvnb[(size_t)m * 512 + tid + 256] = (bf16_t)((v1 - mu) * rstd * lnw[tid + 256] + lnb[tid + 256]);

    // broadcast roped k_pe to all 16 heads of K_pack
    {
        int hh = tid >> 4, j4 = (tid & 15) * 4;
        bf16x4 pk = { (bf16_t)kbuf[j4], (bf16_t)kbuf[j4 + 1],
                      (bf16_t)kbuf[j4 + 2], (bf16_t)kbuf[j4 + 3] };
        *(bf16x4*)(kpack + ((size_t)(b * 16 + hh) * SEQ + t) * 192 + 128 + j4) = pk;
    }
    // rope q_pe in place: 16 heads x 32 pairs
    #pragma unroll
    for (int i = 0; i < 2; ++i) {
        int p = tid + 256 * i;
        int h = p >> 5, j = p & 31;
        float inv = expf(-(float)j * 0.2878231366242554f);
        float ang = pos * inv;
        float c = cosf(ang), sn = sinf(ang);
        size_t base = (size_t)m * 3072 + h * 192 + 128;
        float x1 = q[base + j], x2 = q[base + 32 + j];
        q[base + j]      = x1 * c - x2 * sn;
        q[base + 32 + j] = x2 * c + x1 * sn;
    }
}

// ---------------------------------------------------------------------------
// MFMA flash attention, balanced: block bx handles q-tiles {31-bx, bx}
// (constant 33 K-steps). T14 reg-prefetch of next K/V tile. bf16 inputs.
// ---------------------------------------------------------------------------
__global__ __launch_bounds__(256, 2)
void attn_mfma(const float* __restrict__ q, const bf16_t* __restrict__ kpack,
               const bf16_t* __restrict__ vt, bf16_t* __restrict__ ao) {
    __shared__ bf16_t Ks[64][200];
    __shared__ bf16_t Vts[128][72];
    __shared__ bf16_t Pls[4][16][72];

    const int bx = blockIdx.x, h = blockIdx.y, b = blockIdx.z;
    const int tid = threadIdx.x;
    const int lane = tid & 63, w = tid >> 6;
    const int lr = lane & 15, kh = lane >> 4;
    const size_t bS = (size_t)b * SEQ;
    const bf16_t* kbase = kpack + (size_t)(b * 16 + h) * SEQ * 192;
    const bf16_t* vbase = vt + (size_t)(b * 16 + h) * 128 * SEQ;

    int krow_[6], koff_[6], vd_[4], vt8_[4];
    #pragma unroll
    for (int i = 0; i < 6; ++i) { int c = tid + 256 * i; krow_[i] = c / 24; koff_[i] = (c % 24) * 8; }
    #pragma unroll
    for (int i = 0; i < 4; ++i) { int c = tid + 256 * i; vd_[i] = c >> 3; vt8_[i] = (c & 7) * 8; }

    for (int half = 0; half < 2; ++half) {
        const int qt = half ? bx : (31 - bx);
        const int q0 = qt * 64;
        const int myrow = q0 + w * 16;

        // Q fragments (fp32 -> bf16), 6 k-steps of 32 over 192 dims
        bf16x8 qf[6];
        {
            const float* qrow = q + (bS + myrow + lr) * 3072 + h * 192;
            #pragma unroll
            for (int ks = 0; ks < 6; ++ks) {
                float4 a = *(const float4*)(qrow + ks * 32 + kh * 8);
                float4 c2 = *(const float4*)(qrow + ks * 32 + kh * 8 + 4);
                qf[ks][0] = (bf16_t)a.x;  qf[ks][1] = (bf16_t)a.y;
                qf[ks][2] = (bf16_t)a.z;  qf[ks][3] = (bf16_t)a.w;
                qf[ks][4] = (bf16_t)c2.x; qf[ks][5] = (bf16_t)c2.y;
                qf[ks][6] = (bf16_t)c2.z; qf[ks][7] = (bf16_t)c2.w;
            }
        }

        f32x4 O[8];
        #pragma unroll
        for (int i = 0; i < 8; ++i) O[i] = 0.0f;
        float m_r[4] = { -1e30f, -1e30f, -1e30f, -1e30f };
        float l_r[4] = { 0.0f, 0.0f, 0.0f, 0.0f };

        // prologue: load tile 0 into regs
        bf16x8 rk[6], rv[4];
        #pragma unroll
        for (int i = 0; i < 6; ++i)
            rk[i] = *(const bf16x8*)(kbase + (size_t)krow_[i] * 192 + koff_[i]);
        #pragma unroll
        for (int i = 0; i < 4; ++i)
            rv[i] = *(const bf16x8*)(vbase + (size_t)vd_[i] * SEQ + vt8_[i]);

        for (int kt = 0; kt <= qt; ++kt) {
            __syncthreads();
            #pragma unroll
            for (int i = 0; i < 6; ++i) *(bf16x8*)&Ks[krow_[i]][koff_[i]] = rk[i];
            #pragma unroll
            for (int i = 0; i < 4; ++i) *(bf16x8*)&Vts[vd_[i]][vt8_[i]] = rv[i];
            if (kt < qt) {   // T14: issue next tile's loads; they fly under compute
                const int t1 = (kt + 1) * 64;
                #pragma unroll
                for (int i = 0; i < 6; ++i)
                    rk[i] = *(const bf16x8*)(kbase + (size_t)(t1 + krow_[i]) * 192 + koff_[i]);
                #pragma unroll
                for (int i = 0; i < 4; ++i)
                    rv[i] = *(const bf16x8*)(vbase + (size_t)vd_[i] * SEQ + t1 + vt8_[i]);
            }
            __syncthreads();

            // QK^T
            f32x4 sacc[4];
            #pragma unroll
            for (int j = 0; j < 4; ++j) sacc[j] = 0.0f;
            #pragma unroll
            for (int ks = 0; ks < 6; ++ks)
                #pragma unroll
                for (int j = 0; j < 4; ++j) {
                    bf16x8 bfr = *(const bf16x8*)&Ks[j * 16 + lr][ks * 32 + kh * 8];
                    sacc[j] = __builtin_amdgcn_mfma_f32_16x16x32_bf16(qf[ks], bfr, sacc[j], 0, 0, 0);
                }

            const int t0 = kt * 64;
            float sv[4][4];
            if (kt == qt) {
                #pragma unroll
                for (int j = 0; j < 4; ++j) {
                    int tcol = t0 + j * 16 + lr;
                    #pragma unroll
                    for (int rr = 0; rr < 4; ++rr) {
                        int qrow2 = myrow + kh * 4 + rr;
                        sv[j][rr] = (tcol > qrow2) ? -1e30f : sacc[j][rr] * MLA_SCALE;
                    }
                }
            } else {
                #pragma unroll
                for (int j = 0; j < 4; ++j)
                    #pragma unroll
                    for (int rr = 0; rr < 4; ++rr)
                        sv[j][rr] = sacc[j][rr] * MLA_SCALE;
            }

            // online softmax (rows across 16-lane groups)
            float corr[4];
            #pragma unroll
            for (int rr = 0; rr < 4; ++rr) {
                float mx = fmaxf(fmaxf(sv[0][rr], sv[1][rr]), fmaxf(sv[2][rr], sv[3][rr]));
                mx = fmaxf(mx, __shfl_xor(mx, 1));
                mx = fmaxf(mx, __shfl_xor(mx, 2));
                mx = fmaxf(mx, __shfl_xor(mx, 4));
                mx = fmaxf(mx, __shfl_xor(mx, 8));
                float mnew = fmaxf(m_r[rr], mx);
                float cr = __expf(m_r[rr] - mnew);
                float ps = 0.0f;
                #pragma unroll
                for (int j = 0; j < 4; ++j) {
                    float p = __expf(sv[j][rr] - mnew);
                    sv[j][rr] = p;
                    ps += p;
                }
                ps += __shfl_xor(ps, 1);
                ps += __shfl_xor(ps, 2);
                ps += __shfl_xor(ps, 4);
                ps += __shfl_xor(ps, 8);
                l_r[rr] = l_r[rr] * cr + ps;
                m_r[rr] = mnew;
                corr[rr] = cr;
            }
            #pragma unroll
            for (int dt = 0; dt < 8; ++dt)
                #pragma unroll
                for (int rr = 0; rr < 4; ++rr)
                    O[dt][rr] *= corr[rr];

            // P -> per-wave LDS, re-fragment for PV
            #pragma unroll
            for (int rr = 0; rr < 4; ++rr)
                #pragma unroll
                for (int j = 0; j < 4; ++j)
                    Pls[w][kh * 4 + rr][j * 16 + lr] = (bf16_t)sv[j][rr];
            bf16x8 pa0 = *(const bf16x8*)&Pls[w][lr][kh * 8];
            bf16x8 pa1 = *(const bf16x8*)&Pls[w][lr][32 + kh * 8];
            #pragma unroll
            for (int dt = 0; dt < 8; ++dt) {
                bf16x8 b0 = *(const bf16x8*)&Vts[dt * 16 + lr][kh * 8];
                O[dt] = __builtin_amdgcn_mfma_f32_16x16x32_bf16(pa0, b0, O[dt], 0, 0, 0);
                bf16x8 b1 = *(const bf16x8*)&Vts[dt * 16 + lr][32 + kh * 8];
                O[dt] = __builtin_amdgcn_mfma_f32_16x16x32_bf16(pa1, b1, O[dt], 0, 0, 0);
            }
        }

        // epilogue: bf16 ao
        #pragma unroll
        for (int rr = 0; rr < 4; ++rr) {
            float inv = 1.0f / l_r[rr];
            size_t rowb = (bS + myrow + kh * 4 + rr) * 2048 + h * 128;
            #pragma unroll
            for (int dt = 0; dt < 8; ++dt)
                ao[rowb + dt * 16 + lr] = (bf16_t)(O[dt][rr] * inv);
        }
    }
}

// ---------------------------------------------------------------------------
extern "C" void kernel_launch(void* const* d_in, const int* in_sizes, int n_in,
                              void* d_out, int out_size, void* d_ws, size_t ws_size,
                              hipStream_t stream) {
    const float* x     = (const float*)d_in[0];
    const float* wq    = (const float*)d_in[1];
    const float* wkv_a = (const float*)d_in[2];
    const float* lnw   = (const float*)d_in[3];
    const float* lnb   = (const float*)d_in[4];
    const float* wkv_b = (const float*)d_in[5];
    const float* wo    = (const float*)d_in[6];
    const int* start_pos = (const int*)d_in[7];
    float* out = (float*)d_out;

    char* w8 = (char*)d_ws;
    bf16_t* xb   = (bf16_t*)(w8);                  // 8388608  elems
    bf16_t* wqb  = (bf16_t*)(w8 + 16777216);       // 6291456
    bf16_t* wab  = (bf16_t*)(w8 + 29360128);       // 1179648
    bf16_t* wbb  = (bf16_t*)(w8 + 31719424);       // 2097152
    bf16_t* wob  = (bf16_t*)(w8 + 35913728);       // 4194304
    bf16_t* kvnb = (bf16_t*)(w8 + 44302336);       // 2097152
    bf16_t* kpk  = (bf16_t*)(w8 + 48496640);       // 12582912 (K_pack)
    bf16_t* vtb  = (bf16_t*)(w8 + 73662464);       // 8388608  (Vt)
    bf16_t* aob  = (bf16_t*)(w8 + 90439680);       // 8388608
    float*  qws  = (float*)(w8 + 107216896);       // 12582912 fp32
    float*  kva  = (float*)(w8 + 157548544);       // 2359296  fp32

    // one-shot bf16 conversion of activations-input + all weights
    cvt_f32_bf16<<<2048, 256, 0, stream>>>(x,     xb,  8388608 / 4);
    cvt_f32_bf16<<<2048, 256, 0, stream>>>(wq,    wqb, 6291456 / 4);
    cvt_f32_bf16<<<1152, 256, 0, stream>>>(wkv_a, wab, 1179648 / 4);
    cvt_f32_bf16<<<2048, 256, 0, stream>>>(wkv_b, wbb, 2097152 / 4);
    cvt_f32_bf16<<<2048, 256, 0, stream>>>(wo,    wob, 4194304 / 4);

    // q = x @ wq.T (fp32 out, rope mutates it)
    gemm_nt<<<dim3(24, 32), 256, 0, stream>>>(xb, wqb, qws, 4096, 3072, 2048);
    // kv_all = x @ wkv_a.T
    gemm_nt<<<dim3(5, 32), 256, 0, stream>>>(xb, wab, kva, 4096, 576, 2048);
    // layernorm + rope (+ K_pack rope broadcast)
    rope_ln<<<4096, 256, 0, stream>>>(qws, kva, lnw, lnb, kvnb, kpk, start_pos);
    // k_nope -> K_pack, v -> Vt (transposed), bf16
    gemm_kvb_pack<<<dim3(32, 32), 256, 0, stream>>>(kvnb, wbb, kpk, vtb);
    // balanced MFMA flash attention -> bf16 ao
    attn_mfma<<<dim3(16, 16, 2), 256, 0, stream>>>(qws, kpk, vtb, aob);
    // out = ao @ wo.T
    gemm_nt<<<dim3(16, 32), 256, 0, stream>>>(aob, wob, out, 4096, 2048, 2048);
}

// Round 5
// 331.487 us; speedup vs baseline: 8.3157x; 1.0715x over previous
//
#include <hip/hip_runtime.h>
#include <hip/hip_bf16.h>
#include <math.h>

typedef __bf16 bf16_t;
typedef __bf16 bf16x4 __attribute__((ext_vector_type(4)));
typedef __bf16 bf16x8 __attribute__((ext_vector_type(8)));
typedef float f32x4 __attribute__((ext_vector_type(4)));

#define SEQ 2048
#define MLA_SCALE 0.07216878364870322f
#define LN_EPS 1e-5f

__device__ __forceinline__ void gload_lds16(const bf16_t* g, bf16_t* l) {
    __builtin_amdgcn_global_load_lds(
        (const __attribute__((address_space(1))) uint32_t*)(const void*)g,
        (__attribute__((address_space(3))) uint32_t*)(void*)l, 16, 0, 0);
}

// ---------------------------------------------------------------------------
// fp32 -> bf16 convert (vectorized, grid-stride)
// ---------------------------------------------------------------------------
__global__ __launch_bounds__(256)
void cvt_f32_bf16(const float* __restrict__ in, bf16_t* __restrict__ out, int n4) {
    for (int i = blockIdx.x * 256 + threadIdx.x; i < n4; i += gridDim.x * 256) {
        float4 v = ((const float4*)in)[i];
        bf16x4 p = { (bf16_t)v.x, (bf16_t)v.y, (bf16_t)v.z, (bf16_t)v.w };
        ((bf16x4*)out)[i] = p;
    }
}

// ===========================================================================
// 256x256 8-phase GEMM. C[M,N] = A[M,K] * B[N,K]^T, bf16 in, fp32 acc.
// BK=64, 512 thr (8 waves, 2Mx4N). Per-matrix 4-slot LDS ring of K-half
// tiles (256r x 32k = 16KB). XOR-swizzled reads + matching pre-swizzled
// global source (gload_lds dest stays linear). Counted vmcnt(8) placed
// BEFORE the closing barrier of even phases (cross-wave visibility).
// Requires: M%256==0, N%256==0, K%128==0.
// ===========================================================================
#define G256_PHASE(TAU, KS, MH, HTO, MAT, WAITV)                               \
{                                                                              \
    const int slot_ = (2 * (TAU) + (KS)) & 3;                                  \
    bf16x8 af_[4];                                                             \
    {                                                                          \
        const bf16_t* ab_ = As + slot_ * 8192 +                                \
                            (wm2 * 128 + (MH) * 64 + lr) * 32 + rdcol;         \
        _Pragma("unroll")                                                      \
        for (int f = 0; f < 4; ++f) af_[f] = *(const bf16x8*)(ab_ + f * 512);  \
    }                                                                          \
    if ((MH) == 0) {                                                           \
        const bf16_t* bb_ = Bs + slot_ * 8192 + (wn2 * 64 + lr) * 32 + rdcol;  \
        _Pragma("unroll")                                                      \
        for (int f = 0; f < 4; ++f) bq[f] = *(const bf16x8*)(bb_ + f * 512);   \
    }                                                                          \
    if ((MAT) == 0) stageA(2 * T + 3 + (HTO)); else stageB(2 * T + 3 + (HTO)); \
    __builtin_amdgcn_s_barrier();                                              \
    asm volatile("" ::: "memory");                                             \
    __builtin_amdgcn_s_setprio(1);                                             \
    _Pragma("unroll")                                                          \
    for (int f = 0; f < 4; ++f)                                                \
        _Pragma("unroll")                                                      \
        for (int n = 0; n < 4; ++n)                                            \
            acc[(MH) * 4 + f][n] = __builtin_amdgcn_mfma_f32_16x16x32_bf16(    \
                af_[f], bq[n], acc[(MH) * 4 + f][n], 0, 0, 0);                 \
    __builtin_amdgcn_s_setprio(0);                                             \
    asm volatile("" ::: "memory");                                             \
    if (WAITV) asm volatile("s_waitcnt vmcnt(8)" ::: "memory");                \
    __builtin_amdgcn_s_barrier();                                              \
}

template<bool PACK>
__global__ __launch_bounds__(512, 2)
void gemm256(const bf16_t* __restrict__ A, const bf16_t* __restrict__ B,
             float* __restrict__ C, bf16_t* __restrict__ kpack,
             bf16_t* __restrict__ vt, int N, int K) {
    __shared__ __attribute__((aligned(16))) bf16_t As[32768];  // 64KB
    __shared__ __attribute__((aligned(16))) bf16_t Bs[32768];  // 64KB
    __shared__ __attribute__((aligned(16))) bf16_t Ds[8192];   // dummy sink 16KB

    const int tid = threadIdx.x;
    const int lane = tid & 63, w = tid >> 6;
    const int lr = lane & 15, kh = lane >> 4;
    const int wm2 = w >> 2, wn2 = w & 3;
    const int bm = blockIdx.y, bn = blockIdx.x;
    const int NT = K >> 6;

    // read swizzle: 16B slot index = kh ^ (row-bits[2:1]); 2-way max aliasing
    const int rdcol = 8 * (kh ^ ((lr >> 1) & 3));
    // stage: lane covers row (lane>>2), slot (lane&3); source pre-swizzled
    const int strow = (w << 5) + (lane >> 2);
    const int scol = 8 * ((lane & 3) ^ ((lane >> 3) & 3));

    f32x4 acc[8][4];
    #pragma unroll
    for (int i = 0; i < 8; ++i)
        #pragma unroll
        for (int j = 0; j < 4; ++j) acc[i][j] = 0.0f;

    auto stageA = [&](int ht) {
        int hs = (ht < 2 * NT) ? ht : (2 * NT - 1);
        int tau = hs >> 1, kap = hs & 1;
        const bf16_t* g = A + (size_t)(bm * 256 + strow) * K + tau * 64 + kap * 32 + scol;
        bf16_t* l = (ht < 2 * NT) ? (As + (ht & 3) * 8192 + w * 1024) : (Ds + w * 1024);
        gload_lds16(g, l);
        gload_lds16(g + (size_t)16 * K, l + 512);
    };
    auto stageB = [&](int ht) {
        int hs = (ht < 2 * NT) ? ht : (2 * NT - 1);
        int tau = hs >> 1, kap = hs & 1;
        const bf16_t* g = B + (size_t)(bn * 256 + strow) * K + tau * 64 + kap * 32 + scol;
        bf16_t* l = (ht < 2 * NT) ? (Bs + (ht & 3) * 8192 + w * 1024) : (Ds + w * 1024);
        gload_lds16(g, l);
        gload_lds16(g + (size_t)16 * K, l + 512);
    };

    // prologue: stage half-tiles 0,1,2 (A and B) = 12 loads/wave, then
    // ensure half-tile 0 (4 oldest) landed BEFORE the barrier (all waves).
    stageA(0); stageB(0); stageA(1); stageB(1); stageA(2); stageB(2);
    asm volatile("s_waitcnt vmcnt(8)" ::: "memory");
    __builtin_amdgcn_s_barrier();

    for (int it = 0; it < (NT >> 1); ++it) {
        const int T = 2 * it;
        bf16x8 bq[4];
        G256_PHASE(T,     0, 0, 0, 0, 0)
        G256_PHASE(T,     0, 1, 0, 1, 1)
        G256_PHASE(T,     1, 0, 1, 0, 0)
        G256_PHASE(T,     1, 1, 1, 1, 1)
        G256_PHASE(T + 1, 0, 0, 2, 0, 0)
        G256_PHASE(T + 1, 0, 1, 2, 1, 1)
        G256_PHASE(T + 1, 1, 0, 3, 0, 0)
        G256_PHASE(T + 1, 1, 1, 3, 1, 1)
    }

    // epilogue: C/D layout col=lane&15, row=(lane>>4)*4+reg
    const int rg = kh * 4;
    if (!PACK) {
        #pragma unroll
        for (int mf = 0; mf < 8; ++mf)
            #pragma unroll
            for (int nf = 0; nf < 4; ++nf) {
                size_t row0 = (size_t)(bm * 256 + wm2 * 128 + mf * 16 + rg);
                int col = bn * 256 + wn2 * 64 + nf * 16 + lr;
                #pragma unroll
                for (int rr = 0; rr < 4; ++rr)
                    C[(row0 + rr) * N + col] = acc[mf][nf][rr];
            }
    } else {
        // bn == head. d<128 -> K_pack[b,h,t,192]; else Vt[b,h,d-128,t]
        const int h = bn;
        #pragma unroll
        for (int mf = 0; mf < 8; ++mf)
            #pragma unroll
            for (int nf = 0; nf < 4; ++nf) {
                int d = wn2 * 64 + nf * 16 + lr;
                int trow = bm * 256 + wm2 * 128 + mf * 16 + rg;
                int b = trow >> 11, t = trow & 2047;
                if (d < 128) {
                    bf16_t* p = kpack + ((size_t)(b * 16 + h) * SEQ + t) * 192 + d;
                    #pragma unroll
                    for (int rr = 0; rr < 4; ++rr)
                        p[rr * 192] = (bf16_t)acc[mf][nf][rr];
                } else {
                    bf16x4 pv = { (bf16_t)acc[mf][nf][0], (bf16_t)acc[mf][nf][1],
                                  (bf16_t)acc[mf][nf][2], (bf16_t)acc[mf][nf][3] };
                    *(bf16x4*)(vt + ((size_t)(b * 16 + h) * 128 + (d - 128)) * SEQ + t) = pv;
                }
            }
    }
}

// ---------------------------------------------------------------------------
// m97-structure 128x128 GEMM (kept for N=576 kv_a and N=2048 wo)
// ---------------------------------------------------------------------------
__device__ __forceinline__ void gemm_core(const bf16_t* __restrict__ A,
                                          const bf16_t* __restrict__ B,
                                          int N, int K, int bm, int bn,
                                          bf16_t* As, bf16_t* Bs,
                                          f32x4 (&acc)[4][4]) {
    const int tid = threadIdx.x;
    const int lane = tid & 63, w = tid >> 6;
    const int lr = lane & 15, kh = lane >> 4;
    const int wm = (w >> 1) * 64, wn = (w & 1) * 64;
    const int subrow = lane >> 2;
    const int colel = (lane & 3) * 8;

    const int rA = bm * 128 + 32 * w + subrow;
    const int rB = bn * 128 + 32 * w + subrow;
    const int rb1 = (rB < N) ? rB : (N - 1);
    const int rb2 = (rB + 16 < N) ? (rB + 16) : (N - 1);

    for (int kt = 0; kt < K; kt += 32) {
        __syncthreads();
        gload_lds16(A + (size_t)rA * K + kt + colel,        As + (2 * w) * 512);
        gload_lds16(A + (size_t)(rA + 16) * K + kt + colel, As + (2 * w + 1) * 512);
        gload_lds16(B + (size_t)rb1 * K + kt + colel,       Bs + (2 * w) * 512);
        gload_lds16(B + (size_t)rb2 * K + kt + colel,       Bs + (2 * w + 1) * 512);
        __syncthreads();
        bf16x8 af[4], bfr[4];
        #pragma unroll
        for (int im = 0; im < 4; ++im)
            af[im] = *(const bf16x8*)(As + (wm + im * 16 + lr) * 32 + kh * 8);
        #pragma unroll
        for (int jn = 0; jn < 4; ++jn)
            bfr[jn] = *(const bf16x8*)(Bs + (wn + jn * 16 + lr) * 32 + kh * 8);
        #pragma unroll
        for (int im = 0; im < 4; ++im)
            #pragma unroll
            for (int jn = 0; jn < 4; ++jn)
                acc[im][jn] = __builtin_amdgcn_mfma_f32_16x16x32_bf16(
                    af[im], bfr[jn], acc[im][jn], 0, 0, 0);
    }
}

__global__ __launch_bounds__(256)
void gemm_nt(const bf16_t* __restrict__ A, const bf16_t* __restrict__ B,
             float* __restrict__ C, int M, int N, int K) {
    __shared__ bf16_t As[4096], Bs[4096];
    f32x4 acc[4][4];
    #pragma unroll
    for (int i = 0; i < 4; ++i)
        #pragma unroll
        for (int j = 0; j < 4; ++j) acc[i][j] = 0.0f;
    gemm_core(A, B, N, K, blockIdx.y, blockIdx.x, As, Bs, acc);

    const int tid = threadIdx.x, lane = tid & 63, w = tid >> 6;
    const int lr = lane & 15, rg = (lane >> 4) * 4;
    const int wm = (w >> 1) * 64, wn = (w & 1) * 64;
    #pragma unroll
    for (int im = 0; im < 4; ++im)
        #pragma unroll
        for (int jn = 0; jn < 4; ++jn) {
            int col = blockIdx.x * 128 + wn + jn * 16 + lr;
            if (col >= N) continue;
            size_t rowb = (size_t)(blockIdx.y * 128 + wm + im * 16 + rg);
            #pragma unroll
            for (int rr = 0; rr < 4; ++rr)
                C[(rowb + rr) * N + col] = acc[im][jn][rr];
        }
}

// ---------------------------------------------------------------------------
// Fused: layernorm(kv)->kvnb (bf16), rope(k_pe)->K_pack broadcast, rope(q_pe)
// ---------------------------------------------------------------------------
__global__ __launch_bounds__(256)
void rope_ln(float* __restrict__ q, const float* __restrict__ kv_all,
             const float* __restrict__ lnw, const float* __restrict__ lnb,
             bf16_t* __restrict__ kvnb, bf16_t* __restrict__ kpack,
             const int* __restrict__ start_pos) {
    const int m = blockIdx.x;
    const int tid = threadIdx.x;
    const int b = m >> 11, t = m & 2047;
    const float pos = (float)(start_pos[0] + t);
    __shared__ float red[8];
    __shared__ float stats[2];
    __shared__ float kbuf[64];

    const float* kvrow = kv_all + (size_t)m * 576;
    float v0 = kvrow[tid], v1 = kvrow[tid + 256];
    float ssum = v0 + v1, ssq = v0 * v0 + v1 * v1;
    for (int off = 32; off > 0; off >>= 1) {
        ssum += __shfl_down(ssum, off);
        ssq  += __shfl_down(ssq, off);
    }
    const int lane = tid & 63, wid = tid >> 6;
    if (lane == 0) { red[wid] = ssum; red[4 + wid] = ssq; }
    __syncthreads();
    if (tid == 0) {
        float ts = red[0] + red[1] + red[2] + red[3];
        float tq = red[4] + red[5] + red[6] + red[7];
        float mu = ts * (1.0f / 512.0f);
        float var = tq * (1.0f / 512.0f) - mu * mu;
        stats[0] = mu;
        stats[1] = rsqrtf(var + LN_EPS);
    }
    if (tid < 32) {
        int j = tid;
        float inv = expf(-(float)j * 0.2878231366242554f);  // 10000^(-j/32)
        float ang = pos * inv;
        float c = cosf(ang), sn = sinf(ang);
        float x1 = kvrow[512 + j], x2 = kvrow[544 + j];
        kbuf[j]      = x1 * c - x2 * sn;
        kbuf[32 + j] = x2 * c + x1 * sn;
    }
    __syncthreads();
    float mu = stats[0], rstd = stats[1];
    kvnb[(size_t)m * 512 + tid]       = (bf16_t)((v0 - mu) * rstd * lnw[tid] + lnb[tid]);
    kvnb[(size_t)m * 512 + tid + 256] = (bf16_t)((v1 - mu) * rstd * lnw[tid + 256] + lnb[tid + 256]);

    {
        int hh = tid >> 4, j4 = (tid & 15) * 4;
        bf16x4 pk = { (bf16_t)kbuf[j4], (bf16_t)kbuf[j4 + 1],
                      (bf16_t)kbuf[j4 + 2], (bf16_t)kbuf[j4 + 3] };
        *(bf16x4*)(kpack + ((size_t)(b * 16 + hh) * SEQ + t) * 192 + 128 + j4) = pk;
    }
    #pragma unroll
    for (int i = 0; i < 2; ++i) {
        int p = tid + 256 * i;
        int h = p >> 5, j = p & 31;
        float inv = expf(-(float)j * 0.2878231366242554f);
        float ang = pos * inv;
        float c = cosf(ang), sn = sinf(ang);
        size_t base = (size_t)m * 3072 + h * 192 + 128;
        float x1 = q[base + j], x2 = q[base + 32 + j];
        q[base + j]      = x1 * c - x2 * sn;
        q[base + 32 + j] = x2 * c + x1 * sn;
    }
}

// ---------------------------------------------------------------------------
// MFMA flash attention (balanced pair of q-tiles; T14 reg-prefetch; setprio)
// ---------------------------------------------------------------------------
__global__ __launch_bounds__(256, 2)
void attn_mfma(const float* __restrict__ q, const bf16_t* __restrict__ kpack,
               const bf16_t* __restrict__ vt, bf16_t* __restrict__ ao) {
    __shared__ bf16_t Ks[64][200];
    __shared__ bf16_t Vts[128][72];
    __shared__ bf16_t Pls[4][16][72];

    const int bx = blockIdx.x, h = blockIdx.y, b = blockIdx.z;
    const int tid = threadIdx.x;
    const int lane = tid & 63, w = tid >> 6;
    const int lr = lane & 15, kh = lane >> 4;
    const size_t bS = (size_t)b * SEQ;
    const bf16_t* kbase = kpack + (size_t)(b * 16 + h) * SEQ * 192;
    const bf16_t* vbase = vt + (size_t)(b * 16 + h) * 128 * SEQ;

    int krow_[6], koff_[6], vd_[4], vt8_[4];
    #pragma unroll
    for (int i = 0; i < 6; ++i) { int c = tid + 256 * i; krow_[i] = c / 24; koff_[i] = (c % 24) * 8; }
    #pragma unroll
    for (int i = 0; i < 4; ++i) { int c = tid + 256 * i; vd_[i] = c >> 3; vt8_[i] = (c & 7) * 8; }

    for (int half = 0; half < 2; ++half) {
        const int qt = half ? bx : (31 - bx);
        const int q0 = qt * 64;
        const int myrow = q0 + w * 16;

        bf16x8 qf[6];
        {
            const float* qrow = q + (bS + myrow + lr) * 3072 + h * 192;
            #pragma unroll
            for (int ks = 0; ks < 6; ++ks) {
                float4 a = *(const float4*)(qrow + ks * 32 + kh * 8);
                float4 c2 = *(const float4*)(qrow + ks * 32 + kh * 8 + 4);
                qf[ks][0] = (bf16_t)a.x;  qf[ks][1] = (bf16_t)a.y;
                qf[ks][2] = (bf16_t)a.z;  qf[ks][3] = (bf16_t)a.w;
                qf[ks][4] = (bf16_t)c2.x; qf[ks][5] = (bf16_t)c2.y;
                qf[ks][6] = (bf16_t)c2.z; qf[ks][7] = (bf16_t)c2.w;
            }
        }

        f32x4 O[8];
        #pragma unroll
        for (int i = 0; i < 8; ++i) O[i] = 0.0f;
        float m_r[4] = { -1e30f, -1e30f, -1e30f, -1e30f };
        float l_r[4] = { 0.0f, 0.0f, 0.0f, 0.0f };

        bf16x8 rk[6], rv[4];
        #pragma unroll
        for (int i = 0; i < 6; ++i)
            rk[i] = *(const bf16x8*)(kbase + (size_t)krow_[i] * 192 + koff_[i]);
        #pragma unroll
        for (int i = 0; i < 4; ++i)
            rv[i] = *(const bf16x8*)(vbase + (size_t)vd_[i] * SEQ + vt8_[i]);

        for (int kt = 0; kt <= qt; ++kt) {
            __syncthreads();
            #pragma unroll
            for (int i = 0; i < 6; ++i) *(bf16x8*)&Ks[krow_[i]][koff_[i]] = rk[i];
            #pragma unroll
            for (int i = 0; i < 4; ++i) *(bf16x8*)&Vts[vd_[i]][vt8_[i]] = rv[i];
            if (kt < qt) {
                const int t1 = (kt + 1) * 64;
                #pragma unroll
                for (int i = 0; i < 6; ++i)
                    rk[i] = *(const bf16x8*)(kbase + (size_t)(t1 + krow_[i]) * 192 + koff_[i]);
                #pragma unroll
                for (int i = 0; i < 4; ++i)
                    rv[i] = *(const bf16x8*)(vbase + (size_t)vd_[i] * SEQ + t1 + vt8_[i]);
            }
            __syncthreads();

            f32x4 sacc[4];
            #pragma unroll
            for (int j = 0; j < 4; ++j) sacc[j] = 0.0f;
            __builtin_amdgcn_s_setprio(1);
            #pragma unroll
            for (int ks = 0; ks < 6; ++ks)
                #pragma unroll
                for (int j = 0; j < 4; ++j) {
                    bf16x8 bfr = *(const bf16x8*)&Ks[j * 16 + lr][ks * 32 + kh * 8];
                    sacc[j] = __builtin_amdgcn_mfma_f32_16x16x32_bf16(qf[ks], bfr, sacc[j], 0, 0, 0);
                }
            __builtin_amdgcn_s_setprio(0);

            const int t0 = kt * 64;
            float sv[4][4];
            if (kt == qt) {
                #pragma unroll
                for (int j = 0; j < 4; ++j) {
                    int tcol = t0 + j * 16 + lr;
                    #pragma unroll
                    for (int rr = 0; rr < 4; ++rr) {
                        int qrow2 = myrow + kh * 4 + rr;
                        sv[j][rr] = (tcol > qrow2) ? -1e30f : sacc[j][rr] * MLA_SCALE;
                    }
                }
            } else {
                #pragma unroll
                for (int j = 0; j < 4; ++j)
                    #pragma unroll
                    for (int rr = 0; rr < 4; ++rr)
                        sv[j][rr] = sacc[j][rr] * MLA_SCALE;
            }

            float corr[4];
            #pragma unroll
            for (int rr = 0; rr < 4; ++rr) {
                float mx = fmaxf(fmaxf(sv[0][rr], sv[1][rr]), fmaxf(sv[2][rr], sv[3][rr]));
                mx = fmaxf(mx, __shfl_xor(mx, 1));
                mx = fmaxf(mx, __shfl_xor(mx, 2));
                mx = fmaxf(mx, __shfl_xor(mx, 4));
                mx = fmaxf(mx, __shfl_xor(mx, 8));
                float mnew = fmaxf(m_r[rr], mx);
                float cr = __expf(m_r[rr] - mnew);
                float ps = 0.0f;
                #pragma unroll
                for (int j = 0; j < 4; ++j) {
                    float p = __expf(sv[j][rr] - mnew);
                    sv[j][rr] = p;
                    ps += p;
                }
                ps += __shfl_xor(ps, 1);
                ps += __shfl_xor(ps, 2);
                ps += __shfl_xor(ps, 4);
                ps += __shfl_xor(ps, 8);
                l_r[rr] = l_r[rr] * cr + ps;
                m_r[rr] = mnew;
                corr[rr] = cr;
            }
            #pragma unroll
            for (int dt = 0; dt < 8; ++dt)
                #pragma unroll
                for (int rr = 0; rr < 4; ++rr)
                    O[dt][rr] *= corr[rr];

            #pragma unroll
            for (int rr = 0; rr < 4; ++rr)
                #pragma unroll
                for (int j = 0; j < 4; ++j)
                    Pls[w][kh * 4 + rr][j * 16 + lr] = (bf16_t)sv[j][rr];
            bf16x8 pa0 = *(const bf16x8*)&Pls[w][lr][kh * 8];
            bf16x8 pa1 = *(const bf16x8*)&Pls[w][lr][32 + kh * 8];
            __builtin_amdgcn_s_setprio(1);
            #pragma unroll
            for (int dt = 0; dt < 8; ++dt) {
                bf16x8 b0 = *(const bf16x8*)&Vts[dt * 16 + lr][kh * 8];
                O[dt] = __builtin_amdgcn_mfma_f32_16x16x32_bf16(pa0, b0, O[dt], 0, 0, 0);
                bf16x8 b1 = *(const bf16x8*)&Vts[dt * 16 + lr][32 + kh * 8];
                O[dt] = __builtin_amdgcn_mfma_f32_16x16x32_bf16(pa1, b1, O[dt], 0, 0, 0);
            }
            __builtin_amdgcn_s_setprio(0);
        }

        #pragma unroll
        for (int rr = 0; rr < 4; ++rr) {
            float inv = 1.0f / l_r[rr];
            size_t rowb = (bS + myrow + kh * 4 + rr) * 2048 + h * 128;
            #pragma unroll
            for (int dt = 0; dt < 8; ++dt)
                ao[rowb + dt * 16 + lr] = (bf16_t)(O[dt][rr] * inv);
        }
    }
}

// ---------------------------------------------------------------------------
extern "C" void kernel_launch(void* const* d_in, const int* in_sizes, int n_in,
                              void* d_out, int out_size, void* d_ws, size_t ws_size,
                              hipStream_t stream) {
    const float* x     = (const float*)d_in[0];
    const float* wq    = (const float*)d_in[1];
    const float* wkv_a = (const float*)d_in[2];
    const float* lnw   = (const float*)d_in[3];
    const float* lnb   = (const float*)d_in[4];
    const float* wkv_b = (const float*)d_in[5];
    const float* wo    = (const float*)d_in[6];
    const int* start_pos = (const int*)d_in[7];
    float* out = (float*)d_out;

    char* w8 = (char*)d_ws;
    bf16_t* xb   = (bf16_t*)(w8);                  // 8388608  elems
    bf16_t* wqb  = (bf16_t*)(w8 + 16777216);       // 6291456
    bf16_t* wab  = (bf16_t*)(w8 + 29360128);       // 1179648
    bf16_t* wbb  = (bf16_t*)(w8 + 31719424);       // 2097152
    bf16_t* wob  = (bf16_t*)(w8 + 35913728);       // 4194304
    bf16_t* kvnb = (bf16_t*)(w8 + 44302336);       // 2097152
    bf16_t* kpk  = (bf16_t*)(w8 + 48496640);       // 12582912 (K_pack)
    bf16_t* vtb  = (bf16_t*)(w8 + 73662464);       // 8388608  (Vt)
    bf16_t* aob  = (bf16_t*)(w8 + 90439680);       // 8388608
    float*  qws  = (float*)(w8 + 107216896);       // 12582912 fp32
    float*  kva  = (float*)(w8 + 157548544);       // 2359296  fp32

    cvt_f32_bf16<<<2048, 256, 0, stream>>>(x,     xb,  8388608 / 4);
    cvt_f32_bf16<<<2048, 256, 0, stream>>>(wq,    wqb, 6291456 / 4);
    cvt_f32_bf16<<<1152, 256, 0, stream>>>(wkv_a, wab, 1179648 / 4);
    cvt_f32_bf16<<<2048, 256, 0, stream>>>(wkv_b, wbb, 2097152 / 4);
    cvt_f32_bf16<<<2048, 256, 0, stream>>>(wo,    wob, 4194304 / 4);

    // q = x @ wq.T  (256^2 8-phase)
    gemm256<false><<<dim3(12, 16), 512, 0, stream>>>(xb, wqb, qws, nullptr, nullptr, 3072, 2048);
    // kv_all = x @ wkv_a.T (128^2, N=576)
    gemm_nt<<<dim3(5, 32), 256, 0, stream>>>(xb, wab, kva, 4096, 576, 2048);
    // layernorm + rope
    rope_ln<<<4096, 256, 0, stream>>>(qws, kva, lnw, lnb, kvnb, kpk, start_pos);
    // k_nope/v -> K_pack/Vt (256^2 8-phase + pack epilogue)
    gemm256<true><<<dim3(16, 16), 512, 0, stream>>>(kvnb, wbb, nullptr, kpk, vtb, 4096, 512);
    // attention
    attn_mfma<<<dim3(16, 16, 2), 256, 0, stream>>>(qws, kpk, vtb, aob);
    // out = ao @ wo.T (128^2)
    gemm_nt<<<dim3(16, 32), 256, 0, stream>>>(aob, wob, out, 4096, 2048, 2048);
}

// Round 6
// 308.546 us; speedup vs baseline: 8.9339x; 1.0744x over previous
//
#include <hip/hip_runtime.h>
#include <hip/hip_bf16.h>
#include <math.h>

typedef __bf16 bf16_t;
typedef __bf16 bf16x2 __attribute__((ext_vector_type(2)));
typedef __bf16 bf16x4 __attribute__((ext_vector_type(4)));
typedef __bf16 bf16x8 __attribute__((ext_vector_type(8)));
typedef float f32x4 __attribute__((ext_vector_type(4)));

#define SEQ 2048
#define MLA_SCALE 0.07216878364870322f
#define LN_EPS 1e-5f

__device__ __forceinline__ void gload_lds16(const bf16_t* g, bf16_t* l) {
    __builtin_amdgcn_global_load_lds(
        (const __attribute__((address_space(1))) uint32_t*)(const void*)g,
        (__attribute__((address_space(3))) uint32_t*)(void*)l, 16, 0, 0);
}

// ---------------------------------------------------------------------------
// fp32 -> bf16 convert (vectorized, grid-stride)
// ---------------------------------------------------------------------------
__global__ __launch_bounds__(256)
void cvt_f32_bf16(const float* __restrict__ in, bf16_t* __restrict__ out, int n4) {
    for (int i = blockIdx.x * 256 + threadIdx.x; i < n4; i += gridDim.x * 256) {
        float4 v = ((const float4*)in)[i];
        bf16x4 p = { (bf16_t)v.x, (bf16_t)v.y, (bf16_t)v.z, (bf16_t)v.w };
        ((bf16x4*)out)[i] = p;
    }
}

// ===========================================================================
// 256x256 8-phase GEMM. C[M,N] = A[M,K] * B[N,K]^T, bf16 in, fp32 acc.
// MODE 0: fp32 C.  MODE 1: kvb pack (K_pack + Vt).  MODE 2: q bf16 head-major.
// ===========================================================================
#define G256_PHASE(TAU, KS, MH, HTO, MAT, WAITV)                               \
{                                                                              \
    const int slot_ = (2 * (TAU) + (KS)) & 3;                                  \
    bf16x8 af_[4];                                                             \
    {                                                                          \
        const bf16_t* ab_ = As + slot_ * 8192 +                                \
                            (wm2 * 128 + (MH) * 64 + lr) * 32 + rdcol;         \
        _Pragma("unroll")                                                      \
        for (int f = 0; f < 4; ++f) af_[f] = *(const bf16x8*)(ab_ + f * 512);  \
    }                                                                          \
    if ((MH) == 0) {                                                           \
        const bf16_t* bb_ = Bs + slot_ * 8192 + (wn2 * 64 + lr) * 32 + rdcol;  \
        _Pragma("unroll")                                                      \
        for (int f = 0; f < 4; ++f) bq[f] = *(const bf16x8*)(bb_ + f * 512);   \
    }                                                                          \
    if ((MAT) == 0) stageA(2 * T + 3 + (HTO)); else stageB(2 * T + 3 + (HTO)); \
    __builtin_amdgcn_s_barrier();                                              \
    asm volatile("" ::: "memory");                                             \
    __builtin_amdgcn_s_setprio(1);                                             \
    _Pragma("unroll")                                                          \
    for (int f = 0; f < 4; ++f)                                                \
        _Pragma("unroll")                                                      \
        for (int n = 0; n < 4; ++n)                                            \
            acc[(MH) * 4 + f][n] = __builtin_amdgcn_mfma_f32_16x16x32_bf16(    \
                af_[f], bq[n], acc[(MH) * 4 + f][n], 0, 0, 0);                 \
    __builtin_amdgcn_s_setprio(0);                                             \
    asm volatile("" ::: "memory");                                             \
    if (WAITV) asm volatile("s_waitcnt vmcnt(8)" ::: "memory");                \
    __builtin_amdgcn_s_barrier();                                              \
}

template<int MODE>
__global__ __launch_bounds__(512, 2)
void gemm256(const bf16_t* __restrict__ A, const bf16_t* __restrict__ B,
             float* __restrict__ C, bf16_t* __restrict__ out0,
             bf16_t* __restrict__ out1, int N, int K) {
    __shared__ __attribute__((aligned(16))) bf16_t As[32768];
    __shared__ __attribute__((aligned(16))) bf16_t Bs[32768];
    __shared__ __attribute__((aligned(16))) bf16_t Ds[8192];

    const int tid = threadIdx.x;
    const int lane = tid & 63, w = tid >> 6;
    const int lr = lane & 15, kh = lane >> 4;
    const int wm2 = w >> 2, wn2 = w & 3;
    const int bm = blockIdx.y, bn = blockIdx.x;
    const int NT = K >> 6;

    const int rdcol = 8 * (kh ^ ((lr >> 1) & 3));
    const int strow = (w << 5) + (lane >> 2);
    const int scol = 8 * ((lane & 3) ^ ((lane >> 3) & 3));

    f32x4 acc[8][4];
    #pragma unroll
    for (int i = 0; i < 8; ++i)
        #pragma unroll
        for (int j = 0; j < 4; ++j) acc[i][j] = 0.0f;

    auto stageA = [&](int ht) {
        int hs = (ht < 2 * NT) ? ht : (2 * NT - 1);
        int tau = hs >> 1, kap = hs & 1;
        const bf16_t* g = A + (size_t)(bm * 256 + strow) * K + tau * 64 + kap * 32 + scol;
        bf16_t* l = (ht < 2 * NT) ? (As + (ht & 3) * 8192 + w * 1024) : (Ds + w * 1024);
        gload_lds16(g, l);
        gload_lds16(g + (size_t)16 * K, l + 512);
    };
    auto stageB = [&](int ht) {
        int hs = (ht < 2 * NT) ? ht : (2 * NT - 1);
        int tau = hs >> 1, kap = hs & 1;
        const bf16_t* g = B + (size_t)(bn * 256 + strow) * K + tau * 64 + kap * 32 + scol;
        bf16_t* l = (ht < 2 * NT) ? (Bs + (ht & 3) * 8192 + w * 1024) : (Ds + w * 1024);
        gload_lds16(g, l);
        gload_lds16(g + (size_t)16 * K, l + 512);
    };

    stageA(0); stageB(0); stageA(1); stageB(1); stageA(2); stageB(2);
    asm volatile("s_waitcnt vmcnt(8)" ::: "memory");
    __builtin_amdgcn_s_barrier();

    for (int it = 0; it < (NT >> 1); ++it) {
        const int T = 2 * it;
        bf16x8 bq[4];
        G256_PHASE(T,     0, 0, 0, 0, 0)
        G256_PHASE(T,     0, 1, 0, 1, 1)
        G256_PHASE(T,     1, 0, 1, 0, 0)
        G256_PHASE(T,     1, 1, 1, 1, 1)
        G256_PHASE(T + 1, 0, 0, 2, 0, 0)
        G256_PHASE(T + 1, 0, 1, 2, 1, 1)
        G256_PHASE(T + 1, 1, 0, 3, 0, 0)
        G256_PHASE(T + 1, 1, 1, 3, 1, 1)
    }

    const int rg = kh * 4;
    if (MODE == 0) {
        #pragma unroll
        for (int mf = 0; mf < 8; ++mf)
            #pragma unroll
            for (int nf = 0; nf < 4; ++nf) {
                size_t row0 = (size_t)(bm * 256 + wm2 * 128 + mf * 16 + rg);
                int col = bn * 256 + wn2 * 64 + nf * 16 + lr;
                #pragma unroll
                for (int rr = 0; rr < 4; ++rr)
                    C[(row0 + rr) * N + col] = acc[mf][nf][rr];
            }
    } else if (MODE == 1) {
        // bn == head. d<128 -> K_pack[b,h,t,192]; else Vt[b,h,d-128,t]
        const int h = bn;
        #pragma unroll
        for (int mf = 0; mf < 8; ++mf)
            #pragma unroll
            for (int nf = 0; nf < 4; ++nf) {
                int d = wn2 * 64 + nf * 16 + lr;
                int trow = bm * 256 + wm2 * 128 + mf * 16 + rg;
                int b = trow >> 11, t = trow & 2047;
                if (d < 128) {
                    bf16_t* p = out0 + ((size_t)(b * 16 + h) * SEQ + t) * 192 + d;
                    #pragma unroll
                    for (int rr = 0; rr < 4; ++rr)
                        p[rr * 192] = (bf16_t)acc[mf][nf][rr];
                } else {
                    bf16x4 pv = { (bf16_t)acc[mf][nf][0], (bf16_t)acc[mf][nf][1],
                                  (bf16_t)acc[mf][nf][2], (bf16_t)acc[mf][nf][3] };
                    *(bf16x4*)(out1 + ((size_t)(b * 16 + h) * 128 + (d - 128)) * SEQ + t) = pv;
                }
            }
    } else {
        // q pack: bf16 head-major q[b,h,t,192]
        #pragma unroll
        for (int mf = 0; mf < 8; ++mf)
            #pragma unroll
            for (int nf = 0; nf < 4; ++nf) {
                int n = bn * 256 + wn2 * 64 + nf * 16 + lr;
                int h = n / 192, d = n - h * 192;
                int trow = bm * 256 + wm2 * 128 + mf * 16 + rg;
                int b = trow >> 11, t = trow & 2047;
                bf16_t* p = out0 + ((size_t)(b * 16 + h) * SEQ + t) * 192 + d;
                #pragma unroll
                for (int rr = 0; rr < 4; ++rr)
                    p[rr * 192] = (bf16_t)acc[mf][nf][rr];
            }
    }
}

// ---------------------------------------------------------------------------
// m97-structure 128x128 GEMM (kept for N=576 kv_a and N=2048 wo)
// ---------------------------------------------------------------------------
__device__ __forceinline__ void gemm_core(const bf16_t* __restrict__ A,
                                          const bf16_t* __restrict__ B,
                                          int N, int K, int bm, int bn,
                                          bf16_t* As, bf16_t* Bs,
                                          f32x4 (&acc)[4][4]) {
    const int tid = threadIdx.x;
    const int lane = tid & 63, w = tid >> 6;
    const int lr = lane & 15, kh = lane >> 4;
    const int wm = (w >> 1) * 64, wn = (w & 1) * 64;
    const int subrow = lane >> 2;
    const int colel = (lane & 3) * 8;

    const int rA = bm * 128 + 32 * w + subrow;
    const int rB = bn * 128 + 32 * w + subrow;
    const int rb1 = (rB < N) ? rB : (N - 1);
    const int rb2 = (rB + 16 < N) ? (rB + 16) : (N - 1);

    for (int kt = 0; kt < K; kt += 32) {
        __syncthreads();
        gload_lds16(A + (size_t)rA * K + kt + colel,        As + (2 * w) * 512);
        gload_lds16(A + (size_t)(rA + 16) * K + kt + colel, As + (2 * w + 1) * 512);
        gload_lds16(B + (size_t)rb1 * K + kt + colel,       Bs + (2 * w) * 512);
        gload_lds16(B + (size_t)rb2 * K + kt + colel,       Bs + (2 * w + 1) * 512);
        __syncthreads();
        bf16x8 af[4], bfr[4];
        #pragma unroll
        for (int im = 0; im < 4; ++im)
            af[im] = *(const bf16x8*)(As + (wm + im * 16 + lr) * 32 + kh * 8);
        #pragma unroll
        for (int jn = 0; jn < 4; ++jn)
            bfr[jn] = *(const bf16x8*)(Bs + (wn + jn * 16 + lr) * 32 + kh * 8);
        #pragma unroll
        for (int im = 0; im < 4; ++im)
            #pragma unroll
            for (int jn = 0; jn < 4; ++jn)
                acc[im][jn] = __builtin_amdgcn_mfma_f32_16x16x32_bf16(
                    af[im], bfr[jn], acc[im][jn], 0, 0, 0);
    }
}

__global__ __launch_bounds__(256)
void gemm_nt(const bf16_t* __restrict__ A, const bf16_t* __restrict__ B,
             float* __restrict__ C, int M, int N, int K) {
    __shared__ bf16_t As[4096], Bs[4096];
    f32x4 acc[4][4];
    #pragma unroll
    for (int i = 0; i < 4; ++i)
        #pragma unroll
        for (int j = 0; j < 4; ++j) acc[i][j] = 0.0f;
    gemm_core(A, B, N, K, blockIdx.y, blockIdx.x, As, Bs, acc);

    const int tid = threadIdx.x, lane = tid & 63, w = tid >> 6;
    const int lr = lane & 15, rg = (lane >> 4) * 4;
    const int wm = (w >> 1) * 64, wn = (w & 1) * 64;
    #pragma unroll
    for (int im = 0; im < 4; ++im)
        #pragma unroll
        for (int jn = 0; jn < 4; ++jn) {
            int col = blockIdx.x * 128 + wn + jn * 16 + lr;
            if (col >= N) continue;
            size_t rowb = (size_t)(blockIdx.y * 128 + wm + im * 16 + rg);
            #pragma unroll
            for (int rr = 0; rr < 4; ++rr)
                C[(rowb + rr) * N + col] = acc[im][jn][rr];
        }
}

// ---------------------------------------------------------------------------
// Fused: layernorm(kv)->kvnb (bf16), rope(k_pe)->K_pack broadcast,
// rope cos/sin table (b==0 blocks). Does NOT touch q anymore.
// ---------------------------------------------------------------------------
__global__ __launch_bounds__(256)
void rope_ln(const float* __restrict__ kv_all,
             const float* __restrict__ lnw, const float* __restrict__ lnb,
             bf16_t* __restrict__ kvnb, bf16_t* __restrict__ kpack,
             float2* __restrict__ rope_cs, const int* __restrict__ start_pos) {
    const int m = blockIdx.x;
    const int tid = threadIdx.x;
    const int b = m >> 11, t = m & 2047;
    const float pos = (float)(start_pos[0] + t);
    __shared__ float red[8];
    __shared__ float stats[2];
    __shared__ float kbuf[64];

    const float* kvrow = kv_all + (size_t)m * 576;
    float v0 = kvrow[tid], v1 = kvrow[tid + 256];
    float ssum = v0 + v1, ssq = v0 * v0 + v1 * v1;
    for (int off = 32; off > 0; off >>= 1) {
        ssum += __shfl_down(ssum, off);
        ssq  += __shfl_down(ssq, off);
    }
    const int lane = tid & 63, wid = tid >> 6;
    if (lane == 0) { red[wid] = ssum; red[4 + wid] = ssq; }
    __syncthreads();
    if (tid == 0) {
        float ts = red[0] + red[1] + red[2] + red[3];
        float tq = red[4] + red[5] + red[6] + red[7];
        float mu = ts * (1.0f / 512.0f);
        float var = tq * (1.0f / 512.0f) - mu * mu;
        stats[0] = mu;
        stats[1] = rsqrtf(var + LN_EPS);
    }
    if (tid < 32) {
        int j = tid;
        float inv = expf(-(float)j * 0.2878231366242554f);  // 10000^(-j/32)
        float ang = pos * inv;
        float c = cosf(ang), sn = sinf(ang);
        float x1 = kvrow[512 + j], x2 = kvrow[544 + j];
        kbuf[j]      = x1 * c - x2 * sn;
        kbuf[32 + j] = x2 * c + x1 * sn;
        if (b == 0) rope_cs[t * 32 + j] = make_float2(c, sn);
    }
    __syncthreads();
    float mu = stats[0], rstd = stats[1];
    kvnb[(size_t)m * 512 + tid]       = (bf16_t)((v0 - mu) * rstd * lnw[tid] + lnb[tid]);
    kvnb[(size_t)m * 512 + tid + 256] = (bf16_t)((v1 - mu) * rstd * lnw[tid + 256] + lnb[tid + 256]);

    {
        int hh = tid >> 4, j4 = (tid & 15) * 4;
        bf16x4 pk = { (bf16_t)kbuf[j4], (bf16_t)kbuf[j4 + 1],
                      (bf16_t)kbuf[j4 + 2], (bf16_t)kbuf[j4 + 3] };
        *(bf16x4*)(kpack + ((size_t)(b * 16 + hh) * SEQ + t) * 192 + 128 + j4) = pk;
    }
}

// ---------------------------------------------------------------------------
// MFMA flash attention, swapped-operand QK^T (lane-local softmax).
// mfma(K_frag, Q_frag) -> D[t][q]: q = lane&15 (fixed per lane),
// t = j*16 + kh*4 + rr. Softmax reduce: 15 in-lane ops + shfl_xor(16,32).
// Q is bf16 head-major [b,h,t,192]; rope applied on load via cos/sin table.
// ---------------------------------------------------------------------------
__global__ __launch_bounds__(256, 2)
void attn_mfma(const bf16_t* __restrict__ qb, const bf16_t* __restrict__ kpack,
               const bf16_t* __restrict__ vt, const float2* __restrict__ rope_cs,
               bf16_t* __restrict__ ao) {
    __shared__ bf16_t Ks[64][200];
    __shared__ bf16_t Vts[128][72];
    __shared__ bf16_t Pls[4][16][72];

    const int bx = blockIdx.x, h = blockIdx.y, b = blockIdx.z;
    const int tid = threadIdx.x;
    const int lane = tid & 63, w = tid >> 6;
    const int lr = lane & 15, kh = lane >> 4;
    const size_t bS = (size_t)b * SEQ;
    const bf16_t* kbase = kpack + (size_t)(b * 16 + h) * SEQ * 192;
    const bf16_t* vbase = vt + (size_t)(b * 16 + h) * 128 * SEQ;

    int krow_[6], koff_[6], vd_[4], vt8_[4];
    #pragma unroll
    for (int i = 0; i < 6; ++i) { int c = tid + 256 * i; krow_[i] = c / 24; koff_[i] = (c % 24) * 8; }
    #pragma unroll
    for (int i = 0; i < 4; ++i) { int c = tid + 256 * i; vd_[i] = c >> 3; vt8_[i] = (c & 7) * 8; }

    for (int half = 0; half < 2; ++half) {
        const int qt = half ? bx : (31 - bx);
        const int q0 = qt * 64;
        const int myrow = q0 + w * 16;
        const int qabs = myrow + lr;       // this lane's q row (softmax state row)

        // Q fragments: bf16 direct + in-register rope on ks=4/5 (dims 128..192)
        bf16x8 qf[6];
        {
            const bf16_t* qrow = qb + ((size_t)(b * 16 + h) * SEQ + qabs) * 192;
            #pragma unroll
            for (int ks = 0; ks < 6; ++ks)
                qf[ks] = *(const bf16x8*)(qrow + ks * 32 + kh * 8);
            const float2* csp = rope_cs + (size_t)qabs * 32 + kh * 8;
            #pragma unroll
            for (int i = 0; i < 8; ++i) {
                float2 cs = csp[i];
                float x1 = (float)qf[4][i], x2 = (float)qf[5][i];
                qf[4][i] = (bf16_t)(x1 * cs.x - x2 * cs.y);
                qf[5][i] = (bf16_t)(x2 * cs.x + x1 * cs.y);
            }
        }

        f32x4 O[8];
        #pragma unroll
        for (int i = 0; i < 8; ++i) O[i] = 0.0f;
        float m_r = -1e30f, l_r = 0.0f;

        bf16x8 rk[6], rv[4];
        #pragma unroll
        for (int i = 0; i < 6; ++i)
            rk[i] = *(const bf16x8*)(kbase + (size_t)krow_[i] * 192 + koff_[i]);
        #pragma unroll
        for (int i = 0; i < 4; ++i)
            rv[i] = *(const bf16x8*)(vbase + (size_t)vd_[i] * SEQ + vt8_[i]);

        for (int kt = 0; kt <= qt; ++kt) {
            __syncthreads();
            #pragma unroll
            for (int i = 0; i < 6; ++i) *(bf16x8*)&Ks[krow_[i]][koff_[i]] = rk[i];
            #pragma unroll
            for (int i = 0; i < 4; ++i) *(bf16x8*)&Vts[vd_[i]][vt8_[i]] = rv[i];
            if (kt < qt) {
                const int t1 = (kt + 1) * 64;
                #pragma unroll
                for (int i = 0; i < 6; ++i)
                    rk[i] = *(const bf16x8*)(kbase + (size_t)(t1 + krow_[i]) * 192 + koff_[i]);
                #pragma unroll
                for (int i = 0; i < 4; ++i)
                    rv[i] = *(const bf16x8*)(vbase + (size_t)vd_[i] * SEQ + t1 + vt8_[i]);
            }
            __syncthreads();

            // swapped QK^T: D[t][q], q = lr (lane-fixed)
            f32x4 sacc[4];
            #pragma unroll
            for (int j = 0; j < 4; ++j) sacc[j] = 0.0f;
            __builtin_amdgcn_s_setprio(1);
            #pragma unroll
            for (int ks = 0; ks < 6; ++ks)
                #pragma unroll
                for (int j = 0; j < 4; ++j) {
                    bf16x8 kf = *(const bf16x8*)&Ks[j * 16 + lr][ks * 32 + kh * 8];
                    sacc[j] = __builtin_amdgcn_mfma_f32_16x16x32_bf16(kf, qf[ks], sacc[j], 0, 0, 0);
                }
            __builtin_amdgcn_s_setprio(0);

            const int t0 = kt * 64;
            float p[16];   // p[j*4+rr] = S[t = t0+16j+4kh+rr][q = qabs]
            if (kt == qt) {
                #pragma unroll
                for (int j = 0; j < 4; ++j)
                    #pragma unroll
                    for (int rr = 0; rr < 4; ++rr) {
                        int tabs = t0 + j * 16 + kh * 4 + rr;
                        p[j * 4 + rr] = (tabs > qabs) ? -1e30f : sacc[j][rr] * MLA_SCALE;
                    }
            } else {
                #pragma unroll
                for (int j = 0; j < 4; ++j)
                    #pragma unroll
                    for (int rr = 0; rr < 4; ++rr)
                        p[j * 4 + rr] = sacc[j][rr] * MLA_SCALE;
            }

            // lane-local softmax: 16 in-lane + cross-kh (xor16, xor32)
            float mx = p[0];
            #pragma unroll
            for (int e = 1; e < 16; ++e) mx = fmaxf(mx, p[e]);
            mx = fmaxf(mx, __shfl_xor(mx, 16));
            mx = fmaxf(mx, __shfl_xor(mx, 32));
            float mnew = fmaxf(m_r, mx);
            float cr = __expf(m_r - mnew);
            float ps = 0.0f;
            #pragma unroll
            for (int e = 0; e < 16; ++e) {
                p[e] = __expf(p[e] - mnew);
                ps += p[e];
            }
            ps += __shfl_xor(ps, 16);
            ps += __shfl_xor(ps, 32);
            l_r = l_r * cr + ps;
            m_r = mnew;

            // redistribute corr to output rows (q_out = kh*4+rr -> held by lane lr=q_out)
            float corr[4];
            #pragma unroll
            for (int rr = 0; rr < 4; ++rr)
                corr[rr] = __shfl(cr, kh * 4 + rr);
            #pragma unroll
            for (int dt = 0; dt < 8; ++dt)
                #pragma unroll
                for (int rr = 0; rr < 4; ++rr)
                    O[dt][rr] *= corr[rr];

            // P -> LDS (packed bf16x2): Pls[w][q=lr][t = 16j+4kh+2*rr2{,+1}]
            #pragma unroll
            for (int j = 0; j < 4; ++j)
                #pragma unroll
                for (int rr2 = 0; rr2 < 2; ++rr2) {
                    bf16x2 pp = { (bf16_t)p[j * 4 + 2 * rr2], (bf16_t)p[j * 4 + 2 * rr2 + 1] };
                    *(bf16x2*)&Pls[w][lr][j * 16 + kh * 4 + 2 * rr2] = pp;
                }
            // PV: A = P[q][t] (row=lr=q ✓), B = Vt[d][t]; O layout unchanged
            bf16x8 pa0 = *(const bf16x8*)&Pls[w][lr][kh * 8];
            bf16x8 pa1 = *(const bf16x8*)&Pls[w][lr][32 + kh * 8];
            __builtin_amdgcn_s_setprio(1);
            #pragma unroll
            for (int dt = 0; dt < 8; ++dt) {
                bf16x8 b0 = *(const bf16x8*)&Vts[dt * 16 + lr][kh * 8];
                O[dt] = __builtin_amdgcn_mfma_f32_16x16x32_bf16(pa0, b0, O[dt], 0, 0, 0);
                bf16x8 b1 = *(const bf16x8*)&Vts[dt * 16 + lr][32 + kh * 8];
                O[dt] = __builtin_amdgcn_mfma_f32_16x16x32_bf16(pa1, b1, O[dt], 0, 0, 0);
            }
            __builtin_amdgcn_s_setprio(0);
        }

        // epilogue: O rows q = myrow + kh*4 + rr; l for that q held at lane lr=kh*4+rr
        float linv[4];
        #pragma unroll
        for (int rr = 0; rr < 4; ++rr)
            linv[rr] = 1.0f / __shfl(l_r, kh * 4 + rr);
        #pragma unroll
        for (int rr = 0; rr < 4; ++rr) {
            size_t rowb = (bS + myrow + kh * 4 + rr) * 2048 + h * 128;
            #pragma unroll
            for (int dt = 0; dt < 8; ++dt)
                ao[rowb + dt * 16 + lr] = (bf16_t)(O[dt][rr] * linv[rr]);
        }
    }
}

// ---------------------------------------------------------------------------
extern "C" void kernel_launch(void* const* d_in, const int* in_sizes, int n_in,
                              void* d_out, int out_size, void* d_ws, size_t ws_size,
                              hipStream_t stream) {
    const float* x     = (const float*)d_in[0];
    const float* wq    = (const float*)d_in[1];
    const float* wkv_a = (const float*)d_in[2];
    const float* lnw   = (const float*)d_in[3];
    const float* lnb   = (const float*)d_in[4];
    const float* wkv_b = (const float*)d_in[5];
    const float* wo    = (const float*)d_in[6];
    const int* start_pos = (const int*)d_in[7];
    float* out = (float*)d_out;

    char* w8 = (char*)d_ws;
    bf16_t* xb   = (bf16_t*)(w8);                  // 16777216 B
    bf16_t* wqb  = (bf16_t*)(w8 + 16777216);       // 12582912 B
    bf16_t* wab  = (bf16_t*)(w8 + 29360128);       //  2359296 B
    bf16_t* wbb  = (bf16_t*)(w8 + 31719424);       //  4194304 B
    bf16_t* wob  = (bf16_t*)(w8 + 35913728);       //  8388608 B
    bf16_t* kvnb = (bf16_t*)(w8 + 44302336);       //  4194304 B
    bf16_t* kpk  = (bf16_t*)(w8 + 48496640);       // 25165824 B (K_pack)
    bf16_t* vtb  = (bf16_t*)(w8 + 73662464);       // 16777216 B (Vt)
    bf16_t* aob  = (bf16_t*)(w8 + 90439680);       // 16777216 B
    bf16_t* qbh  = (bf16_t*)(w8 + 107216896);      // 25165824 B (q bf16 head-major)
    float*  kva  = (float*)(w8 + 132382720);       //  9437184 B fp32
    float2* rcs  = (float2*)(w8 + 141819904);      //   524288 B (rope table)

    cvt_f32_bf16<<<2048, 256, 0, stream>>>(x,     xb,  8388608 / 4);
    cvt_f32_bf16<<<2048, 256, 0, stream>>>(wq,    wqb, 6291456 / 4);
    cvt_f32_bf16<<<1152, 256, 0, stream>>>(wkv_a, wab, 1179648 / 4);
    cvt_f32_bf16<<<2048, 256, 0, stream>>>(wkv_b, wbb, 2097152 / 4);
    cvt_f32_bf16<<<2048, 256, 0, stream>>>(wo,    wob, 4194304 / 4);

    // q = x @ wq.T -> bf16 head-major q[b,h,t,192] (rope NOT yet applied)
    gemm256<2><<<dim3(12, 16), 512, 0, stream>>>(xb, wqb, nullptr, qbh, nullptr, 3072, 2048);
    // kv_all = x @ wkv_a.T (128^2, N=576)
    gemm_nt<<<dim3(5, 32), 256, 0, stream>>>(xb, wab, kva, 4096, 576, 2048);
    // layernorm + k_pe rope + rope table
    rope_ln<<<4096, 256, 0, stream>>>(kva, lnw, lnb, kvnb, kpk, rcs, start_pos);
    // k_nope/v -> K_pack/Vt
    gemm256<1><<<dim3(16, 16), 512, 0, stream>>>(kvnb, wbb, nullptr, kpk, vtb, 4096, 512);
    // attention (rope on Q applied in-register)
    attn_mfma<<<dim3(16, 16, 2), 256, 0, stream>>>(qbh, kpk, vtb, rcs, aob);
    // out = ao @ wo.T (128^2)
    gemm_nt<<<dim3(16, 32), 256, 0, stream>>>(aob, wob, out, 4096, 2048, 2048);
}

// Round 7
// 287.601 us; speedup vs baseline: 9.5846x; 1.0728x over previous
//
#include <hip/hip_runtime.h>
#include <hip/hip_bf16.h>
#include <math.h>

typedef __bf16 bf16_t;
typedef __bf16 bf16x2 __attribute__((ext_vector_type(2)));
typedef __bf16 bf16x4 __attribute__((ext_vector_type(4)));
typedef __bf16 bf16x8 __attribute__((ext_vector_type(8)));
typedef float f32x4 __attribute__((ext_vector_type(4)));

#define SEQ 2048
#define MLA_SCALE 0.07216878364870322f
#define LN_EPS 1e-5f

__device__ __forceinline__ void gload_lds16(const bf16_t* g, bf16_t* l) {
    __builtin_amdgcn_global_load_lds(
        (const __attribute__((address_space(1))) uint32_t*)(const void*)g,
        (__attribute__((address_space(3))) uint32_t*)(void*)l, 16, 0, 0);
}

// bijective XCD-aware block swizzle: same-XCD blocks share A-panels (few bm)
// and sweep all bn. Requires total%8==0 and (total/8)%nbn==0.
__device__ __forceinline__ void xcd_map(int bid, int total, int nbn,
                                        int& bm, int& bn) {
    int per = total >> 3;
    int cbm = per / nbn;
    int xcd = bid & 7, s = bid >> 3;
    int q = s / nbn;
    bm = xcd * cbm + q;
    bn = s - q * nbn;
}

// ---------------------------------------------------------------------------
// fp32 -> bf16 convert (vectorized, grid-stride)
// ---------------------------------------------------------------------------
__global__ __launch_bounds__(256)
void cvt_f32_bf16(const float* __restrict__ in, bf16_t* __restrict__ out, int n4) {
    for (int i = blockIdx.x * 256 + threadIdx.x; i < n4; i += gridDim.x * 256) {
        float4 v = ((const float4*)in)[i];
        bf16x4 p = { (bf16_t)v.x, (bf16_t)v.y, (bf16_t)v.z, (bf16_t)v.w };
        ((bf16x4*)out)[i] = p;
    }
}

// ===========================================================================
// 256x256 8-phase GEMM. C[M,N] = A[M,K] * B[N,K]^T, bf16 in, fp32 acc.
// MODE 0: fp32 C.  MODE 1: kvb pack (K_pack + Vt).  MODE 2: q bf16 head-major.
// 1D grid + XCD swizzle.
// ===========================================================================
#define G256_PHASE(TAU, KS, MH, HTO, MAT, WAITV)                               \
{                                                                              \
    const int slot_ = (2 * (TAU) + (KS)) & 3;                                  \
    bf16x8 af_[4];                                                             \
    {                                                                          \
        const bf16_t* ab_ = As + slot_ * 8192 +                                \
                            (wm2 * 128 + (MH) * 64 + lr) * 32 + rdcol;         \
        _Pragma("unroll")                                                      \
        for (int f = 0; f < 4; ++f) af_[f] = *(const bf16x8*)(ab_ + f * 512);  \
    }                                                                          \
    if ((MH) == 0) {                                                           \
        const bf16_t* bb_ = Bs + slot_ * 8192 + (wn2 * 64 + lr) * 32 + rdcol;  \
        _Pragma("unroll")                                                      \
        for (int f = 0; f < 4; ++f) bq[f] = *(const bf16x8*)(bb_ + f * 512);   \
    }                                                                          \
    if ((MAT) == 0) stageA(2 * T + 3 + (HTO)); else stageB(2 * T + 3 + (HTO)); \
    __builtin_amdgcn_s_barrier();                                              \
    asm volatile("" ::: "memory");                                             \
    __builtin_amdgcn_s_setprio(1);                                             \
    _Pragma("unroll")                                                          \
    for (int f = 0; f < 4; ++f)                                                \
        _Pragma("unroll")                                                      \
        for (int n = 0; n < 4; ++n)                                            \
            acc[(MH) * 4 + f][n] = __builtin_amdgcn_mfma_f32_16x16x32_bf16(    \
                af_[f], bq[n], acc[(MH) * 4 + f][n], 0, 0, 0);                 \
    __builtin_amdgcn_s_setprio(0);                                             \
    asm volatile("" ::: "memory");                                             \
    if (WAITV) asm volatile("s_waitcnt vmcnt(8)" ::: "memory");                \
    __builtin_amdgcn_s_barrier();                                              \
}

template<int MODE>
__global__ __launch_bounds__(512, 2)
void gemm256(const bf16_t* __restrict__ A, const bf16_t* __restrict__ B,
             float* __restrict__ C, bf16_t* __restrict__ out0,
             bf16_t* __restrict__ out1, int N, int K, int total, int nbn) {
    __shared__ __attribute__((aligned(16))) bf16_t As[32768];
    __shared__ __attribute__((aligned(16))) bf16_t Bs[32768];
    __shared__ __attribute__((aligned(16))) bf16_t Ds[8192];

    const int tid = threadIdx.x;
    const int lane = tid & 63, w = tid >> 6;
    const int lr = lane & 15, kh = lane >> 4;
    const int wm2 = w >> 2, wn2 = w & 3;
    int bm, bn;
    xcd_map(blockIdx.x, total, nbn, bm, bn);
    const int NT = K >> 6;

    const int rdcol = 8 * (kh ^ ((lr >> 1) & 3));
    const int strow = (w << 5) + (lane >> 2);
    const int scol = 8 * ((lane & 3) ^ ((lane >> 3) & 3));

    f32x4 acc[8][4];
    #pragma unroll
    for (int i = 0; i < 8; ++i)
        #pragma unroll
        for (int j = 0; j < 4; ++j) acc[i][j] = 0.0f;

    auto stageA = [&](int ht) {
        int hs = (ht < 2 * NT) ? ht : (2 * NT - 1);
        int tau = hs >> 1, kap = hs & 1;
        const bf16_t* g = A + (size_t)(bm * 256 + strow) * K + tau * 64 + kap * 32 + scol;
        bf16_t* l = (ht < 2 * NT) ? (As + (ht & 3) * 8192 + w * 1024) : (Ds + w * 1024);
        gload_lds16(g, l);
        gload_lds16(g + (size_t)16 * K, l + 512);
    };
    auto stageB = [&](int ht) {
        int hs = (ht < 2 * NT) ? ht : (2 * NT - 1);
        int tau = hs >> 1, kap = hs & 1;
        const bf16_t* g = B + (size_t)(bn * 256 + strow) * K + tau * 64 + kap * 32 + scol;
        bf16_t* l = (ht < 2 * NT) ? (Bs + (ht & 3) * 8192 + w * 1024) : (Ds + w * 1024);
        gload_lds16(g, l);
        gload_lds16(g + (size_t)16 * K, l + 512);
    };

    stageA(0); stageB(0); stageA(1); stageB(1); stageA(2); stageB(2);
    asm volatile("s_waitcnt vmcnt(8)" ::: "memory");
    __builtin_amdgcn_s_barrier();

    for (int it = 0; it < (NT >> 1); ++it) {
        const int T = 2 * it;
        bf16x8 bq[4];
        G256_PHASE(T,     0, 0, 0, 0, 0)
        G256_PHASE(T,     0, 1, 0, 1, 1)
        G256_PHASE(T,     1, 0, 1, 0, 0)
        G256_PHASE(T,     1, 1, 1, 1, 1)
        G256_PHASE(T + 1, 0, 0, 2, 0, 0)
        G256_PHASE(T + 1, 0, 1, 2, 1, 1)
        G256_PHASE(T + 1, 1, 0, 3, 0, 0)
        G256_PHASE(T + 1, 1, 1, 3, 1, 1)
    }

    const int rg = kh * 4;
    if (MODE == 0) {
        #pragma unroll
        for (int mf = 0; mf < 8; ++mf)
            #pragma unroll
            for (int nf = 0; nf < 4; ++nf) {
                size_t row0 = (size_t)(bm * 256 + wm2 * 128 + mf * 16 + rg);
                int col = bn * 256 + wn2 * 64 + nf * 16 + lr;
                #pragma unroll
                for (int rr = 0; rr < 4; ++rr)
                    C[(row0 + rr) * N + col] = acc[mf][nf][rr];
            }
    } else if (MODE == 1) {
        // bn == head. d<128 -> K_pack[b,h,t,192]; else Vt[b,h,d-128,t]
        const int h = bn;
        #pragma unroll
        for (int mf = 0; mf < 8; ++mf)
            #pragma unroll
            for (int nf = 0; nf < 4; ++nf) {
                int d = wn2 * 64 + nf * 16 + lr;
                int trow = bm * 256 + wm2 * 128 + mf * 16 + rg;
                int b = trow >> 11, t = trow & 2047;
                if (d < 128) {
                    bf16_t* p = out0 + ((size_t)(b * 16 + h) * SEQ + t) * 192 + d;
                    #pragma unroll
                    for (int rr = 0; rr < 4; ++rr)
                        p[rr * 192] = (bf16_t)acc[mf][nf][rr];
                } else {
                    bf16x4 pv = { (bf16_t)acc[mf][nf][0], (bf16_t)acc[mf][nf][1],
                                  (bf16_t)acc[mf][nf][2], (bf16_t)acc[mf][nf][3] };
                    *(bf16x4*)(out1 + ((size_t)(b * 16 + h) * 128 + (d - 128)) * SEQ + t) = pv;
                }
            }
    } else {
        // q pack: bf16 head-major q[b,h,t,192]
        #pragma unroll
        for (int mf = 0; mf < 8; ++mf)
            #pragma unroll
            for (int nf = 0; nf < 4; ++nf) {
                int n = bn * 256 + wn2 * 64 + nf * 16 + lr;
                int h = n / 192, d = n - h * 192;
                int trow = bm * 256 + wm2 * 128 + mf * 16 + rg;
                int b = trow >> 11, t = trow & 2047;
                bf16_t* p = out0 + ((size_t)(b * 16 + h) * SEQ + t) * 192 + d;
                #pragma unroll
                for (int rr = 0; rr < 4; ++rr)
                    p[rr * 192] = (bf16_t)acc[mf][nf][rr];
            }
    }
}

// ---------------------------------------------------------------------------
// m97-structure 128x128 GEMM (kept for N=576 kv_a and N=2048 wo), XCD swizzle
// ---------------------------------------------------------------------------
__global__ __launch_bounds__(256)
void gemm_nt(const bf16_t* __restrict__ A, const bf16_t* __restrict__ B,
             float* __restrict__ C, int M, int N, int K, int total, int nbn) {
    __shared__ bf16_t As[4096], Bs[4096];
    int bm, bn;
    xcd_map(blockIdx.x, total, nbn, bm, bn);

    const int tid = threadIdx.x;
    const int lane = tid & 63, w = tid >> 6;
    const int lr = lane & 15, kh = lane >> 4;
    const int wm = (w >> 1) * 64, wn = (w & 1) * 64;
    const int subrow = lane >> 2;
    const int colel = (lane & 3) * 8;

    f32x4 acc[4][4];
    #pragma unroll
    for (int i = 0; i < 4; ++i)
        #pragma unroll
        for (int j = 0; j < 4; ++j) acc[i][j] = 0.0f;

    const int rA = bm * 128 + 32 * w + subrow;
    const int rB = bn * 128 + 32 * w + subrow;
    const int rb1 = (rB < N) ? rB : (N - 1);
    const int rb2 = (rB + 16 < N) ? (rB + 16) : (N - 1);

    for (int kt = 0; kt < K; kt += 32) {
        __syncthreads();
        gload_lds16(A + (size_t)rA * K + kt + colel,        As + (2 * w) * 512);
        gload_lds16(A + (size_t)(rA + 16) * K + kt + colel, As + (2 * w + 1) * 512);
        gload_lds16(B + (size_t)rb1 * K + kt + colel,       Bs + (2 * w) * 512);
        gload_lds16(B + (size_t)rb2 * K + kt + colel,       Bs + (2 * w + 1) * 512);
        __syncthreads();
        bf16x8 af[4], bfr[4];
        #pragma unroll
        for (int im = 0; im < 4; ++im)
            af[im] = *(const bf16x8*)(As + (wm + im * 16 + lr) * 32 + kh * 8);
        #pragma unroll
        for (int jn = 0; jn < 4; ++jn)
            bfr[jn] = *(const bf16x8*)(Bs + (wn + jn * 16 + lr) * 32 + kh * 8);
        #pragma unroll
        for (int im = 0; im < 4; ++im)
            #pragma unroll
            for (int jn = 0; jn < 4; ++jn)
                acc[im][jn] = __builtin_amdgcn_mfma_f32_16x16x32_bf16(
                    af[im], bfr[jn], acc[im][jn], 0, 0, 0);
    }

    const int rg = kh * 4;
    #pragma unroll
    for (int im = 0; im < 4; ++im)
        #pragma unroll
        for (int jn = 0; jn < 4; ++jn) {
            int col = bn * 128 + wn + jn * 16 + lr;
            if (col >= N) continue;
            size_t rowb = (size_t)(bm * 128 + wm + im * 16 + rg);
            #pragma unroll
            for (int rr = 0; rr < 4; ++rr)
                C[(rowb + rr) * N + col] = acc[im][jn][rr];
        }
}

// ---------------------------------------------------------------------------
// Fused: layernorm(kv)->kvnb (bf16), rope(k_pe)->K_pack broadcast,
// rope cos/sin table (b==0 blocks).
// ---------------------------------------------------------------------------
__global__ __launch_bounds__(256)
void rope_ln(const float* __restrict__ kv_all,
             const float* __restrict__ lnw, const float* __restrict__ lnb,
             bf16_t* __restrict__ kvnb, bf16_t* __restrict__ kpack,
             float2* __restrict__ rope_cs, const int* __restrict__ start_pos) {
    const int m = blockIdx.x;
    const int tid = threadIdx.x;
    const int b = m >> 11, t = m & 2047;
    const float pos = (float)(start_pos[0] + t);
    __shared__ float red[8];
    __shared__ float stats[2];
    __shared__ float kbuf[64];

    const float* kvrow = kv_all + (size_t)m * 576;
    float v0 = kvrow[tid], v1 = kvrow[tid + 256];
    float ssum = v0 + v1, ssq = v0 * v0 + v1 * v1;
    for (int off = 32; off > 0; off >>= 1) {
        ssum += __shfl_down(ssum, off);
        ssq  += __shfl_down(ssq, off);
    }
    const int lane = tid & 63, wid = tid >> 6;
    if (lane == 0) { red[wid] = ssum; red[4 + wid] = ssq; }
    __syncthreads();
    if (tid == 0) {
        float ts = red[0] + red[1] + red[2] + red[3];
        float tq = red[4] + red[5] + red[6] + red[7];
        float mu = ts * (1.0f / 512.0f);
        float var = tq * (1.0f / 512.0f) - mu * mu;
        stats[0] = mu;
        stats[1] = rsqrtf(var + LN_EPS);
    }
    if (tid < 32) {
        int j = tid;
        float inv = expf(-(float)j * 0.2878231366242554f);  // 10000^(-j/32)
        float ang = pos * inv;
        float c = cosf(ang), sn = sinf(ang);
        float x1 = kvrow[512 + j], x2 = kvrow[544 + j];
        kbuf[j]      = x1 * c - x2 * sn;
        kbuf[32 + j] = x2 * c + x1 * sn;
        if (b == 0) rope_cs[t * 32 + j] = make_float2(c, sn);
    }
    __syncthreads();
    float mu = stats[0], rstd = stats[1];
    kvnb[(size_t)m * 512 + tid]       = (bf16_t)((v0 - mu) * rstd * lnw[tid] + lnb[tid]);
    kvnb[(size_t)m * 512 + tid + 256] = (bf16_t)((v1 - mu) * rstd * lnw[tid + 256] + lnb[tid + 256]);

    {
        int hh = tid >> 4, j4 = (tid & 15) * 4;
        bf16x4 pk = { (bf16_t)kbuf[j4], (bf16_t)kbuf[j4 + 1],
                      (bf16_t)kbuf[j4 + 2], (bf16_t)kbuf[j4 + 3] };
        *(bf16x4*)(kpack + ((size_t)(b * 16 + hh) * SEQ + t) * 192 + 128 + j4) = pk;
    }
}

// ---------------------------------------------------------------------------
// MFMA flash attention, swapped-operand QK^T (lane-local softmax).
// 1D grid, XCD-grouped: each XCD owns 4 complete (h,b) groups so K/V stays
// in its private L2. T13 defer-max. P-writes bf16x4.
// ---------------------------------------------------------------------------
__global__ __launch_bounds__(256, 2)
void attn_mfma(const bf16_t* __restrict__ qb, const bf16_t* __restrict__ kpack,
               const bf16_t* __restrict__ vt, const float2* __restrict__ rope_cs,
               bf16_t* __restrict__ ao) {
    __shared__ bf16_t Ks[64][200];
    __shared__ bf16_t Vts[128][72];
    __shared__ bf16_t Pls[4][16][72];

    // bid -> (bx, h, b): xcd = bid&7 owns groups g = xcd*4 + (s>>4)
    const int bid = blockIdx.x;
    const int xcd = bid & 7, s = bid >> 3;
    const int g = xcd * 4 + (s >> 4);
    const int bx = s & 15;
    const int h = g & 15, b = g >> 4;

    const int tid = threadIdx.x;
    const int lane = tid & 63, w = tid >> 6;
    const int lr = lane & 15, kh = lane >> 4;
    const size_t bS = (size_t)b * SEQ;
    const bf16_t* kbase = kpack + (size_t)(b * 16 + h) * SEQ * 192;
    const bf16_t* vbase = vt + (size_t)(b * 16 + h) * 128 * SEQ;

    int krow_[6], koff_[6], vd_[4], vt8_[4];
    #pragma unroll
    for (int i = 0; i < 6; ++i) { int c = tid + 256 * i; krow_[i] = c / 24; koff_[i] = (c % 24) * 8; }
    #pragma unroll
    for (int i = 0; i < 4; ++i) { int c = tid + 256 * i; vd_[i] = c >> 3; vt8_[i] = (c & 7) * 8; }

    for (int half = 0; half < 2; ++half) {
        const int qt = half ? bx : (31 - bx);
        const int q0 = qt * 64;
        const int myrow = q0 + w * 16;
        const int qabs = myrow + lr;       // this lane's q row

        // Q fragments: bf16 direct + in-register rope on ks=4/5 (dims 128..192)
        bf16x8 qf[6];
        {
            const bf16_t* qrow = qb + ((size_t)(b * 16 + h) * SEQ + qabs) * 192;
            #pragma unroll
            for (int ks = 0; ks < 6; ++ks)
                qf[ks] = *(const bf16x8*)(qrow + ks * 32 + kh * 8);
            const float2* csp = rope_cs + (size_t)qabs * 32 + kh * 8;
            #pragma unroll
            for (int i = 0; i < 8; ++i) {
                float2 cs = csp[i];
                float x1 = (float)qf[4][i], x2 = (float)qf[5][i];
                qf[4][i] = (bf16_t)(x1 * cs.x - x2 * cs.y);
                qf[5][i] = (bf16_t)(x2 * cs.x + x1 * cs.y);
            }
        }

        f32x4 O[8];
        #pragma unroll
        for (int i = 0; i < 8; ++i) O[i] = 0.0f;
        float m_r = -1e30f, l_r = 0.0f;

        bf16x8 rk[6], rv[4];
        #pragma unroll
        for (int i = 0; i < 6; ++i)
            rk[i] = *(const bf16x8*)(kbase + (size_t)krow_[i] * 192 + koff_[i]);
        #pragma unroll
        for (int i = 0; i < 4; ++i)
            rv[i] = *(const bf16x8*)(vbase + (size_t)vd_[i] * SEQ + vt8_[i]);

        for (int kt = 0; kt <= qt; ++kt) {
            __syncthreads();
            #pragma unroll
            for (int i = 0; i < 6; ++i) *(bf16x8*)&Ks[krow_[i]][koff_[i]] = rk[i];
            #pragma unroll
            for (int i = 0; i < 4; ++i) *(bf16x8*)&Vts[vd_[i]][vt8_[i]] = rv[i];
            if (kt < qt) {
                const int t1 = (kt + 1) * 64;
                #pragma unroll
                for (int i = 0; i < 6; ++i)
                    rk[i] = *(const bf16x8*)(kbase + (size_t)(t1 + krow_[i]) * 192 + koff_[i]);
                #pragma unroll
                for (int i = 0; i < 4; ++i)
                    rv[i] = *(const bf16x8*)(vbase + (size_t)vd_[i] * SEQ + t1 + vt8_[i]);
            }
            __syncthreads();

            // swapped QK^T: D[t][q], q = lr (lane-fixed)
            f32x4 sacc[4];
            #pragma unroll
            for (int j = 0; j < 4; ++j) sacc[j] = 0.0f;
            __builtin_amdgcn_s_setprio(1);
            #pragma unroll
            for (int ks = 0; ks < 6; ++ks)
                #pragma unroll
                for (int j = 0; j < 4; ++j) {
                    bf16x8 kf = *(const bf16x8*)&Ks[j * 16 + lr][ks * 32 + kh * 8];
                    sacc[j] = __builtin_amdgcn_mfma_f32_16x16x32_bf16(kf, qf[ks], sacc[j], 0, 0, 0);
                }
            __builtin_amdgcn_s_setprio(0);

            const int t0 = kt * 64;
            float p[16];   // p[j*4+rr] = S[t = t0+16j+4kh+rr][q = qabs]
            if (kt == qt) {
                #pragma unroll
                for (int j = 0; j < 4; ++j)
                    #pragma unroll
                    for (int rr = 0; rr < 4; ++rr) {
                        int tabs = t0 + j * 16 + kh * 4 + rr;
                        p[j * 4 + rr] = (tabs > qabs) ? -1e30f : sacc[j][rr] * MLA_SCALE;
                    }
            } else {
                #pragma unroll
                for (int j = 0; j < 4; ++j)
                    #pragma unroll
                    for (int rr = 0; rr < 4; ++rr)
                        p[j * 4 + rr] = sacc[j][rr] * MLA_SCALE;
            }

            // row max (in-lane + cross-kh)
            float mx = p[0];
            #pragma unroll
            for (int e = 1; e < 16; ++e) mx = fmaxf(mx, p[e]);
            mx = fmaxf(mx, __shfl_xor(mx, 16));
            mx = fmaxf(mx, __shfl_xor(mx, 32));

            // T13 defer-max: skip rescale if no row grew past m_r + 8
            if (!__all(mx <= m_r + 8.0f)) {
                float mnew = fmaxf(m_r, mx);
                float cr = __expf(m_r - mnew);
                l_r *= cr;
                m_r = mnew;
                float corr[4];
                #pragma unroll
                for (int rr = 0; rr < 4; ++rr)
                    corr[rr] = __shfl(cr, kh * 4 + rr);
                #pragma unroll
                for (int dt = 0; dt < 8; ++dt)
                    #pragma unroll
                    for (int rr = 0; rr < 4; ++rr)
                        O[dt][rr] *= corr[rr];
            }

            float ps = 0.0f;
            #pragma unroll
            for (int e = 0; e < 16; ++e) {
                p[e] = __expf(p[e] - m_r);
                ps += p[e];
            }
            ps += __shfl_xor(ps, 16);
            ps += __shfl_xor(ps, 32);
            l_r += ps;

            // P -> LDS (bf16x4, contiguous t): Pls[w][q=lr][t = 16j+4kh .. +3]
            #pragma unroll
            for (int j = 0; j < 4; ++j) {
                bf16x4 pp = { (bf16_t)p[j * 4], (bf16_t)p[j * 4 + 1],
                              (bf16_t)p[j * 4 + 2], (bf16_t)p[j * 4 + 3] };
                *(bf16x4*)&Pls[w][lr][j * 16 + kh * 4] = pp;
            }
            // PV: A = P[q][t], B = Vt[d][t]
            bf16x8 pa0 = *(const bf16x8*)&Pls[w][lr][kh * 8];
            bf16x8 pa1 = *(const bf16x8*)&Pls[w][lr][32 + kh * 8];
            __builtin_amdgcn_s_setprio(1);
            #pragma unroll
            for (int dt = 0; dt < 8; ++dt) {
                bf16x8 b0 = *(const bf16x8*)&Vts[dt * 16 + lr][kh * 8];
                O[dt] = __builtin_amdgcn_mfma_f32_16x16x32_bf16(pa0, b0, O[dt], 0, 0, 0);
                bf16x8 b1 = *(const bf16x8*)&Vts[dt * 16 + lr][32 + kh * 8];
                O[dt] = __builtin_amdgcn_mfma_f32_16x16x32_bf16(pa1, b1, O[dt], 0, 0, 0);
            }
            __builtin_amdgcn_s_setprio(0);
        }

        // epilogue: O rows q = myrow + kh*4 + rr; l for that q at lane lr=kh*4+rr
        float linv[4];
        #pragma unroll
        for (int rr = 0; rr < 4; ++rr)
            linv[rr] = 1.0f / __shfl(l_r, kh * 4 + rr);
        #pragma unroll
        for (int rr = 0; rr < 4; ++rr) {
            size_t rowb = (bS + myrow + kh * 4 + rr) * 2048 + h * 128;
            #pragma unroll
            for (int dt = 0; dt < 8; ++dt)
                ao[rowb + dt * 16 + lr] = (bf16_t)(O[dt][rr] * linv[rr]);
        }
    }
}

// ---------------------------------------------------------------------------
extern "C" void kernel_launch(void* const* d_in, const int* in_sizes, int n_in,
                              void* d_out, int out_size, void* d_ws, size_t ws_size,
                              hipStream_t stream) {
    const float* x     = (const float*)d_in[0];
    const float* wq    = (const float*)d_in[1];
    const float* wkv_a = (const float*)d_in[2];
    const float* lnw   = (const float*)d_in[3];
    const float* lnb   = (const float*)d_in[4];
    const float* wkv_b = (const float*)d_in[5];
    const float* wo    = (const float*)d_in[6];
    const int* start_pos = (const int*)d_in[7];
    float* out = (float*)d_out;

    char* w8 = (char*)d_ws;
    bf16_t* xb   = (bf16_t*)(w8);                  // 16777216 B
    bf16_t* wqb  = (bf16_t*)(w8 + 16777216);       // 12582912 B
    bf16_t* wab  = (bf16_t*)(w8 + 29360128);       //  2359296 B
    bf16_t* wbb  = (bf16_t*)(w8 + 31719424);       //  4194304 B
    bf16_t* wob  = (bf16_t*)(w8 + 35913728);       //  8388608 B
    bf16_t* kvnb = (bf16_t*)(w8 + 44302336);       //  4194304 B
    bf16_t* kpk  = (bf16_t*)(w8 + 48496640);       // 25165824 B (K_pack)
    bf16_t* vtb  = (bf16_t*)(w8 + 73662464);       // 16777216 B (Vt)
    bf16_t* aob  = (bf16_t*)(w8 + 90439680);       // 16777216 B
    bf16_t* qbh  = (bf16_t*)(w8 + 107216896);      // 25165824 B (q bf16 head-major)
    float*  kva  = (float*)(w8 + 132382720);       //  9437184 B fp32
    float2* rcs  = (float2*)(w8 + 141819904);      //   524288 B (rope table)

    cvt_f32_bf16<<<2048, 256, 0, stream>>>(x,     xb,  8388608 / 4);
    cvt_f32_bf16<<<2048, 256, 0, stream>>>(wq,    wqb, 6291456 / 4);
    cvt_f32_bf16<<<1152, 256, 0, stream>>>(wkv_a, wab, 1179648 / 4);
    cvt_f32_bf16<<<2048, 256, 0, stream>>>(wkv_b, wbb, 2097152 / 4);
    cvt_f32_bf16<<<2048, 256, 0, stream>>>(wo,    wob, 4194304 / 4);

    // q = x @ wq.T -> bf16 head-major q[b,h,t,192]
    gemm256<2><<<192, 512, 0, stream>>>(xb, wqb, nullptr, qbh, nullptr, 3072, 2048, 192, 12);
    // kv_all = x @ wkv_a.T (128^2, N=576)
    gemm_nt<<<160, 256, 0, stream>>>(xb, wab, kva, 4096, 576, 2048, 160, 5);
    // layernorm + k_pe rope + rope table
    rope_ln<<<4096, 256, 0, stream>>>(kva, lnw, lnb, kvnb, kpk, rcs, start_pos);
    // k_nope/v -> K_pack/Vt
    gemm256<1><<<256, 512, 0, stream>>>(kvnb, wbb, nullptr, kpk, vtb, 4096, 512, 256, 16);
    // attention
    attn_mfma<<<512, 256, 0, stream>>>(qbh, kpk, vtb, rcs, aob);
    // out = ao @ wo.T (128^2)
    gemm_nt<<<512, 256, 0, stream>>>(aob, wob, out, 4096, 2048, 2048, 512, 16);
}